// Round 4
// baseline (308.192 us; speedup 1.0000x reference)
//
#include <hip/hip_runtime.h>
#include <math.h>

#define C_IN  128
#define C_HID 64
#define C_OUT 40

#define BSH   5                 // bucket = dst >> BSH  (32 nodes / bucket)
#define NGRP  8                 // XCD groups (blockIdx % 8)
#define SRCB  19                // src packed in low 19 bits (N < 524288)

// ---------------- degree + per-(bucket,group) count ----------------
__global__ void k_deg_count(const int* __restrict__ dst, int* __restrict__ deg,
                            int* __restrict__ bcnt, int e) {
    int i = blockIdx.x * 256 + threadIdx.x;
    if (i < e) {
        int d = dst[i];
        atomicAdd(&deg[d], 1);
        atomicAdd(&bcnt[((d >> BSH) << 3) + (blockIdx.x & (NGRP - 1))], 1);
    }
}

// ---------------- prefix scan over deg -> row_start / cursor ----------------
__global__ void k_scan_partial(const int* __restrict__ deg, int* __restrict__ bsum, int n) {
    __shared__ int lds[1024];
    int i = blockIdx.x * 1024 + threadIdx.x;
    lds[threadIdx.x] = (i < n) ? deg[i] : 0;
    __syncthreads();
    for (int s = 512; s > 0; s >>= 1) {
        if (threadIdx.x < s) lds[threadIdx.x] += lds[threadIdx.x + s];
        __syncthreads();
    }
    if (threadIdx.x == 0) bsum[blockIdx.x] = lds[0];
}

__global__ void k_scan_bsum(int* __restrict__ bsum, int nb) {
    if (threadIdx.x == 0) {
        int run = 0;
        for (int i = 0; i < nb; ++i) { int v = bsum[i]; bsum[i] = run; run += v; }
    }
}

__global__ void k_scan_final(const int* __restrict__ deg, const int* __restrict__ bsum,
                             int* __restrict__ row_start, int* __restrict__ cursor, int n) {
    __shared__ int wsum[16];
    int i = blockIdx.x * 1024 + threadIdx.x;
    int v = (i < n) ? deg[i] : 0;
    int orig = v;
    int lane = threadIdx.x & 63, wid = threadIdx.x >> 6;
    for (int off = 1; off < 64; off <<= 1) { int t = __shfl_up(v, off); if (lane >= off) v += t; }
    if (lane == 63) wsum[wid] = v;
    __syncthreads();
    if (wid == 0) {
        int w = (lane < 16) ? wsum[lane] : 0;
        for (int off = 1; off < 16; off <<= 1) { int t = __shfl_up(w, off); if (lane >= off) w += t; }
        if (lane < 16) wsum[lane] = w;
    }
    __syncthreads();
    int base = bsum[blockIdx.x] + (wid > 0 ? wsum[wid - 1] : 0);
    int excl = base + v - orig;
    if (i < n) { row_start[i] = excl; cursor[i] = excl; }
    if (i == n - 1) row_start[n] = excl + orig;  // == E
}

// ---------------- small single-block scan over bcnt -> bstart, gcur ----------------
__global__ void k_scan_bcnt(const int* __restrict__ bcnt, int* __restrict__ bstart,
                            int* __restrict__ gcur, int m) {
    __shared__ int ws[4];
    __shared__ int carry;
    if (threadIdx.x == 0) carry = 0;
    __syncthreads();
    for (int base = 0; base < m; base += 256) {
        int i = base + threadIdx.x;
        int v = (i < m) ? bcnt[i] : 0;
        int orig = v;
        int lane = threadIdx.x & 63, w = threadIdx.x >> 6;
        for (int o = 1; o < 64; o <<= 1) { int t = __shfl_up(v, o); if (lane >= o) v += t; }
        if (lane == 63) ws[w] = v;
        __syncthreads();
        int add = carry;
        for (int k = 0; k < w; ++k) add += ws[k];
        int excl = add + v - orig;
        if (i < m) { bstart[i] = excl; gcur[i] = excl; }
        __syncthreads();
        if (threadIdx.x == 255) carry = excl + orig;
        __syncthreads();
    }
}

__global__ void k_dinv(const int* __restrict__ deg, float* __restrict__ dinv, int n) {
    int i = blockIdx.x * 256 + threadIdx.x;
    if (i < n) dinv[i] = rsqrtf((float)deg[i] + 1.0f);  // +1 self loop
}

// ---------------- pass A: bucketed coarse scatter (packed 4B records) ----------------
__global__ void k_passA(const int* __restrict__ src, const int* __restrict__ dst,
                        int* __restrict__ gcur, unsigned int* __restrict__ bpack, int e) {
    int i = blockIdx.x * 256 + threadIdx.x;
    if (i < e) {
        int d = dst[i], s = src[i];
        int slot = ((d >> BSH) << 3) + (blockIdx.x & (NGRP - 1));
        int pos = atomicAdd(&gcur[slot], 1);
        bpack[pos] = (unsigned int)s | ((unsigned int)(d & ((1 << BSH) - 1)) << SRCB);
    }
}

// ---------------- pass B: per-bucket fine scatter into final CSR ----------------
__global__ void k_passB(const int* __restrict__ bstart, const unsigned int* __restrict__ bpack,
                        int* __restrict__ cursor, int* __restrict__ csr_src, int nb_buckets, int e) {
    int b = blockIdx.x;
    int beg = bstart[b << 3];
    int end = (b == nb_buckets - 1) ? e : bstart[(b + 1) << 3];
    int base = b << BSH;
    for (int i = beg + threadIdx.x; i < end; i += 256) {
        unsigned int u = bpack[i];
        int s = (int)(u & ((1u << SRCB) - 1));
        int d = base + (int)(u >> SRCB);
        int pos = atomicAdd(&cursor[d], 1);
        csr_src[pos] = s;
    }
}

// ---------------- GEMM1: h1s = dinv[row] * (X @ W1)  (N x 64) ----------------
__global__ void k_gemm1(const float* __restrict__ X, const float* __restrict__ W1,
                        const float* __restrict__ dinv, float* __restrict__ h1s, int n) {
    __shared__ float xt[C_IN][64];        // X^T tile: xt[k][r]       (32 KB)
    __shared__ float wl[C_IN * C_HID];    // W1 as-is: wl[k*64+c]     (32 KB)
    const int t = threadIdx.x;
    const int row0 = blockIdx.x * 64;

    for (int i = t; i < C_IN * C_HID; i += 256) wl[i] = W1[i];
    {
        int r = t >> 2, q = t & 3;
        int grow = row0 + r;
        for (int j = 0; j < 8; ++j) {
            int k = q * 32 + j * 4;
            float4 v = make_float4(0.f, 0.f, 0.f, 0.f);
            if (grow < n) v = *(const float4*)(X + (size_t)grow * C_IN + k);
            xt[k + 0][r] = v.x; xt[k + 1][r] = v.y; xt[k + 2][r] = v.z; xt[k + 3][r] = v.w;
        }
    }
    __syncthreads();

    const int rg = t >> 4, cg = t & 15;
    const int r0 = rg * 4, c0 = cg * 4;
    float acc[4][4] = {};
#pragma unroll 4
    for (int k = 0; k < C_IN; ++k) {
        float4 a = *(const float4*)&xt[k][r0];
        float4 b = *(const float4*)&wl[k * C_HID + c0];
        acc[0][0] = fmaf(a.x, b.x, acc[0][0]); acc[0][1] = fmaf(a.x, b.y, acc[0][1]);
        acc[0][2] = fmaf(a.x, b.z, acc[0][2]); acc[0][3] = fmaf(a.x, b.w, acc[0][3]);
        acc[1][0] = fmaf(a.y, b.x, acc[1][0]); acc[1][1] = fmaf(a.y, b.y, acc[1][1]);
        acc[1][2] = fmaf(a.y, b.z, acc[1][2]); acc[1][3] = fmaf(a.y, b.w, acc[1][3]);
        acc[2][0] = fmaf(a.z, b.x, acc[2][0]); acc[2][1] = fmaf(a.z, b.y, acc[2][1]);
        acc[2][2] = fmaf(a.z, b.z, acc[2][2]); acc[2][3] = fmaf(a.z, b.w, acc[2][3]);
        acc[3][0] = fmaf(a.w, b.x, acc[3][0]); acc[3][1] = fmaf(a.w, b.y, acc[3][1]);
        acc[3][2] = fmaf(a.w, b.z, acc[3][2]); acc[3][3] = fmaf(a.w, b.w, acc[3][3]);
    }
#pragma unroll
    for (int i = 0; i < 4; ++i) {
        int row = row0 + r0 + i;
        if (row < n) {
            float di = dinv[row];
            float4 o = make_float4(di * acc[i][0], di * acc[i][1], di * acc[i][2], di * acc[i][3]);
            *(float4*)(h1s + (size_t)row * C_HID + c0) = o;
        }
    }
}

// ---------------- layer-1 gather-aggregate + bias + relu ----------------
__global__ void k_agg1(const int* __restrict__ row_start, const int* __restrict__ csr_src,
                       const float* __restrict__ h1s, const float* __restrict__ dinv,
                       const float* __restrict__ b1, float* __restrict__ out1, int n) {
    int node = (blockIdx.x * 256 + threadIdx.x) >> 6;
    int lane = threadIdx.x & 63;
    if (node >= n) return;
    int beg = row_start[node], end = row_start[node + 1];
    float a0 = h1s[(size_t)node * C_HID + lane];  // self term (prescaled by dinv[node])
    float a1 = 0.f, a2 = 0.f, a3 = 0.f;
    for (int j = beg; j < end; j += 64) {
        int sv = (j + lane < end) ? csr_src[j + lane] : 0;
        int m = min(64, end - j);
        int k = 0;
        for (; k + 4 <= m; k += 4) {
            int s0 = __shfl(sv, k),     s1 = __shfl(sv, k + 1);
            int s2 = __shfl(sv, k + 2), s3 = __shfl(sv, k + 3);
            a0 += h1s[(size_t)s0 * C_HID + lane];
            a1 += h1s[(size_t)s1 * C_HID + lane];
            a2 += h1s[(size_t)s2 * C_HID + lane];
            a3 += h1s[(size_t)s3 * C_HID + lane];
        }
        for (; k < m; ++k) {
            int s = __shfl(sv, k);
            a0 += h1s[(size_t)s * C_HID + lane];
        }
    }
    float acc = (a0 + a1) + (a2 + a3);
    float v = dinv[node] * acc + b1[lane];
    out1[(size_t)node * C_HID + lane] = v > 0.f ? v : 0.f;
}

// ---------------- GEMM2: h2s = dinv[row] * (out1 @ W2)  (N x 40) ----------------
__global__ void k_gemm2(const float* __restrict__ X2, const float* __restrict__ W2,
                        const float* __restrict__ dinv, float* __restrict__ h2s, int n) {
    __shared__ float xt[C_HID][96];        // X2^T tile (24 KB)
    __shared__ float wl[C_HID * C_OUT];    // W2 (10 KB)
    const int t = threadIdx.x;
    const int row0 = blockIdx.x * 96;

    for (int i = t; i < C_HID * C_OUT; i += 256) wl[i] = W2[i];
    for (int idx = t; idx < 96 * 16; idx += 256) {
        int r = idx >> 4, f4 = idx & 15;
        int grow = row0 + r;
        float4 v = make_float4(0.f, 0.f, 0.f, 0.f);
        if (grow < n) v = *(const float4*)(X2 + (size_t)grow * C_HID + f4 * 4);
        int k = f4 * 4;
        xt[k + 0][r] = v.x; xt[k + 1][r] = v.y; xt[k + 2][r] = v.z; xt[k + 3][r] = v.w;
    }
    __syncthreads();

    if (t >= 240) return;
    const int rg = t / 10, cg = t - rg * 10;   // 24 x 10
    const int r0 = rg * 4, c0 = cg * 4;
    float acc[4][4] = {};
#pragma unroll 4
    for (int k = 0; k < C_HID; ++k) {
        float4 a = *(const float4*)&xt[k][r0];
        float4 b = *(const float4*)&wl[k * C_OUT + c0];
        acc[0][0] = fmaf(a.x, b.x, acc[0][0]); acc[0][1] = fmaf(a.x, b.y, acc[0][1]);
        acc[0][2] = fmaf(a.x, b.z, acc[0][2]); acc[0][3] = fmaf(a.x, b.w, acc[0][3]);
        acc[1][0] = fmaf(a.y, b.x, acc[1][0]); acc[1][1] = fmaf(a.y, b.y, acc[1][1]);
        acc[1][2] = fmaf(a.y, b.z, acc[1][2]); acc[1][3] = fmaf(a.y, b.w, acc[1][3]);
        acc[2][0] = fmaf(a.z, b.x, acc[2][0]); acc[2][1] = fmaf(a.z, b.y, acc[2][1]);
        acc[2][2] = fmaf(a.z, b.z, acc[2][2]); acc[2][3] = fmaf(a.z, b.w, acc[2][3]);
        acc[3][0] = fmaf(a.w, b.x, acc[3][0]); acc[3][1] = fmaf(a.w, b.y, acc[3][1]);
        acc[3][2] = fmaf(a.w, b.z, acc[3][2]); acc[3][3] = fmaf(a.w, b.w, acc[3][3]);
    }
#pragma unroll
    for (int i = 0; i < 4; ++i) {
        int row = row0 + r0 + i;
        if (row < n) {
            float di = dinv[row];
            float4 o = make_float4(di * acc[i][0], di * acc[i][1], di * acc[i][2], di * acc[i][3]);
            *(float4*)(h2s + (size_t)row * C_OUT + c0) = o;
        }
    }
}

// ---------------- layer-2 gather-aggregate + bias + log_softmax ----------------
__global__ void k_agg2(const int* __restrict__ row_start, const int* __restrict__ csr_src,
                       const float* __restrict__ h2s, const float* __restrict__ dinv,
                       const float* __restrict__ b2, float* __restrict__ out, int n) {
    int node = (blockIdx.x * 256 + threadIdx.x) >> 6;
    int lane = threadIdx.x & 63;
    if (node >= n) return;
    int beg = row_start[node], end = row_start[node + 1];
    float a0 = (lane < C_OUT) ? h2s[(size_t)node * C_OUT + lane] : 0.f;
    float a1 = 0.f, a2 = 0.f, a3 = 0.f;
    for (int j = beg; j < end; j += 64) {
        int sv = (j + lane < end) ? csr_src[j + lane] : 0;
        int m = min(64, end - j);
        int k = 0;
        for (; k + 4 <= m; k += 4) {
            int s0 = __shfl(sv, k),     s1 = __shfl(sv, k + 1);
            int s2 = __shfl(sv, k + 2), s3 = __shfl(sv, k + 3);
            if (lane < C_OUT) {
                a0 += h2s[(size_t)s0 * C_OUT + lane];
                a1 += h2s[(size_t)s1 * C_OUT + lane];
                a2 += h2s[(size_t)s2 * C_OUT + lane];
                a3 += h2s[(size_t)s3 * C_OUT + lane];
            }
        }
        for (; k < m; ++k) {
            int s = __shfl(sv, k);
            if (lane < C_OUT) a0 += h2s[(size_t)s * C_OUT + lane];
        }
    }
    float acc = (a0 + a1) + (a2 + a3);
    float v = (lane < C_OUT) ? dinv[node] * acc + b2[lane] : -INFINITY;
    float mx = v;
    for (int off = 32; off; off >>= 1) mx = fmaxf(mx, __shfl_xor(mx, off));
    float ex = (lane < C_OUT) ? expf(v - mx) : 0.f;
    float ss = ex;
    for (int off = 32; off; off >>= 1) ss += __shfl_xor(ss, off);
    float lse = mx + logf(ss);
    if (lane < C_OUT) out[(size_t)node * C_OUT + lane] = v - lse;
}

extern "C" void kernel_launch(void* const* d_in, const int* in_sizes, int n_in,
                              void* d_out, int out_size, void* d_ws, size_t ws_size,
                              hipStream_t stream) {
    const float* X   = (const float*)d_in[0];
    const int*   src = (const int*)d_in[1];
    const int*   dst = (const int*)d_in[2];
    const float* W1  = (const float*)d_in[3];
    const float* b1  = (const float*)d_in[4];
    const float* W2  = (const float*)d_in[5];
    const float* b2  = (const float*)d_in[6];
    float* out = (float*)d_out;

    const int N = in_sizes[0] / C_IN;
    const int E = in_sizes[1];
    const int NB = (N + (1 << BSH) - 1) >> BSH;       // buckets
    const int M  = NB * NGRP;                          // (bucket,group) slots

    // workspace layout
    char* ws = (char*)d_ws;
    size_t off = 0;
    auto take = [&](size_t bytes) { char* p = ws + off; off = (off + bytes + 255) & ~(size_t)255; return p; };
    int*   deg       = (int*)  take((size_t)N * 4);
    int*   row_start = (int*)  take((size_t)(N + 1) * 4);
    int*   cursor    = (int*)  take((size_t)N * 4);
    int*   bsum      = (int*)  take(1024 * 4);
    int*   bcnt      = (int*)  take((size_t)M * 4);
    int*   bstart    = (int*)  take((size_t)M * 4);
    int*   gcur      = (int*)  take((size_t)M * 4);
    unsigned int* bpack = (unsigned int*)take((size_t)E * 4);
    int*   csr_src   = (int*)  take((size_t)E * 4);
    float* dinv      = (float*)take((size_t)N * 4);
    float* h1s       = (float*)take((size_t)N * C_HID * 4);
    float* out1      = (float*)take((size_t)N * C_HID * 4);
    float* h2s       = h1s;  // h1s dead after k_agg1

    const int nb = (N + 1023) / 1024;
    const int eb = (E + 255) / 256;

    hipMemsetAsync(deg, 0, (size_t)N * 4, stream);
    hipMemsetAsync(bcnt, 0, (size_t)M * 4, stream);
    k_deg_count  <<<eb, 256, 0, stream>>>(dst, deg, bcnt, E);
    k_scan_partial<<<nb, 1024, 0, stream>>>(deg, bsum, N);
    k_scan_bsum  <<<1, 64, 0, stream>>>(bsum, nb);
    k_scan_final <<<nb, 1024, 0, stream>>>(deg, bsum, row_start, cursor, N);
    k_scan_bcnt  <<<1, 256, 0, stream>>>(bcnt, bstart, gcur, M);
    k_dinv       <<<(N + 255) / 256, 256, 0, stream>>>(deg, dinv, N);
    k_passA      <<<eb, 256, 0, stream>>>(src, dst, gcur, bpack, E);
    k_passB      <<<NB, 256, 0, stream>>>(bstart, bpack, cursor, csr_src, NB, E);

    k_gemm1      <<<(N + 63) / 64, 256, 0, stream>>>(X, W1, dinv, h1s, N);
    k_agg1       <<<((size_t)N * 64 + 255) / 256, 256, 0, stream>>>(row_start, csr_src, h1s, dinv, b1, out1, N);

    k_gemm2      <<<(N + 95) / 96, 256, 0, stream>>>(out1, W2, dinv, h2s, N);
    k_agg2       <<<((size_t)N * 64 + 255) / 256, 256, 0, stream>>>(row_start, csr_src, h2s, dinv, b2, out, N);
}

// Round 5
// 158.937 us; speedup vs baseline: 1.9391x; 1.9391x over previous
//
#include <hip/hip_runtime.h>
#include <math.h>

#define C_IN  128
#define C_HID 64
#define C_OUT 40

#define BKT_SH 9
#define BKT_N  (1 << BKT_SH)          // 512 nodes per bucket
#define CHUNK  4096                   // edges per hist/binA block
#define EPT    (CHUNK / 256)          // 16 edges per thread

// ---------------- pass 0: per-bucket edge totals (LDS histogram) ----------------
__global__ void k_hist(const int* __restrict__ dst, int* __restrict__ tot, int e, int nbkt) {
    __shared__ int hist[256];
    for (int i = threadIdx.x; i < nbkt; i += 256) hist[i] = 0;
    __syncthreads();
    int base = blockIdx.x * CHUNK;
#pragma unroll
    for (int j = 0; j < EPT; ++j) {
        int i = base + j * 256 + threadIdx.x;
        if (i < e) atomicAdd(&hist[dst[i] >> BKT_SH], 1);
    }
    __syncthreads();
    for (int i = threadIdx.x; i < nbkt; i += 256)
        if (hist[i]) atomicAdd(&tot[i], hist[i]);
}

// ---------------- tiny scan over bucket totals -> bstart, bcur ----------------
__global__ void k_scan_bkt(const int* __restrict__ tot, int* __restrict__ bstart,
                           int* __restrict__ bcur, int nbkt, int e) {
    __shared__ int lds[257];
    for (int i = threadIdx.x; i < nbkt; i += 256) lds[i] = tot[i];
    __syncthreads();
    if (threadIdx.x == 0) {
        int run = 0;
        for (int i = 0; i < nbkt; ++i) { int v = lds[i]; lds[i] = run; run += v; }
        lds[nbkt] = run;   // == e
    }
    __syncthreads();
    for (int i = threadIdx.x; i <= nbkt; i += 256) bstart[i] = lds[i];
    for (int i = threadIdx.x; i < nbkt; i += 256) bcur[i] = lds[i];
}

// ---------------- pass A: LDS multisplit by bucket, coalesced flush ----------------
__global__ void k_binA(const int* __restrict__ src, const int* __restrict__ dst,
                       int* __restrict__ bcur, unsigned int* __restrict__ bpack,
                       int e, int nbkt) {
    __shared__ int hist[256];          // histogram, then local cursors
    __shared__ int excl[256];
    __shared__ int gbase[256];
    __shared__ int wtot[4];
    __shared__ unsigned int stage[CHUNK];
    const int t = threadIdx.x;
    const int base = blockIdx.x * CHUNK;

    for (int i = t; i < nbkt; i += 256) hist[i] = 0;
    __syncthreads();

    unsigned int pk[EPT]; int bk[EPT];
#pragma unroll
    for (int j = 0; j < EPT; ++j) {
        int i = base + j * 256 + t;
        if (i < e) {
            int d = dst[i];
            pk[j] = (unsigned int)src[i] | ((unsigned int)d << 16);   // N < 65536
            bk[j] = d >> BKT_SH;
            atomicAdd(&hist[bk[j]], 1);
        } else bk[j] = -1;
    }
    __syncthreads();

    // parallel exclusive scan of hist[0..nbkt) (nbkt <= 256)
    {
        int lane = t & 63, wv = t >> 6;
        int v = (t < nbkt) ? hist[t] : 0;
        int inc = v;
        for (int o = 1; o < 64; o <<= 1) { int u = __shfl_up(inc, o); if (lane >= o) inc += u; }
        if (lane == 63) wtot[wv] = inc;
        __syncthreads();
        int add = 0;
        for (int k = 0; k < wv; ++k) add += wtot[k];
        if (t < nbkt) excl[t] = add + inc - v;
    }
    __syncthreads();

    // reserve global space per bucket
    for (int i = t; i < nbkt; i += 256) {
        int h = hist[i];
        gbase[i] = h ? atomicAdd(&bcur[i], h) : 0;
    }
    __syncthreads();
    for (int i = t; i < nbkt; i += 256) hist[i] = 0;   // reuse as local cursors
    __syncthreads();

    // LDS scatter into bucket-sorted order
#pragma unroll
    for (int j = 0; j < EPT; ++j) {
        if (bk[j] >= 0) {
            int p = excl[bk[j]] + atomicAdd(&hist[bk[j]], 1);
            stage[p] = pk[j];
        }
    }
    __syncthreads();

    // coalesced flush: consecutive LDS slots in a bucket -> consecutive global
    int nchunk = min(CHUNK, e - base);
    for (int i = t; i < nchunk; i += 256) {
        unsigned int u = stage[i];
        int b = (int)(u >> 16) >> BKT_SH;
        bpack[gbase[b] + (i - excl[b])] = u;
    }
}

// ---------------- pass B: per-bucket counting sort -> deg/dinv/row_start/csr_src ----------------
__global__ void k_binB(const int* __restrict__ bstart, const unsigned int* __restrict__ bpack,
                       int* __restrict__ row_start, float* __restrict__ dinv,
                       int* __restrict__ csr_src, int n, int e, int nbkt) {
    __shared__ int hist[BKT_N];
    __shared__ int excl[BKT_N];
    __shared__ int wtot[4];
    const int t = threadIdx.x;
    const int b = blockIdx.x;
    const int beg = bstart[b], end = bstart[b + 1];
    const int nodebase = b << BKT_SH;
    const int nloc = min(BKT_N, n - nodebase);

    for (int i = t; i < nloc; i += 256) hist[i] = 0;
    __syncthreads();
    for (int i = beg + t; i < end; i += 256)
        atomicAdd(&hist[(int)(bpack[i] >> 16) - nodebase], 1);
    __syncthreads();

    // exclusive scan of hist[0..nloc) in 256-wide passes with carry
    int carry = 0;
    for (int base0 = 0; base0 < nloc; base0 += 256) {
        __syncthreads();
        int idx = base0 + t;
        int v = (idx < nloc) ? hist[idx] : 0;
        int inc = v; int lane = t & 63; int wv = t >> 6;
        for (int o = 1; o < 64; o <<= 1) { int u = __shfl_up(inc, o); if (lane >= o) inc += u; }
        if (lane == 63) wtot[wv] = inc;
        __syncthreads();
        int add = carry;
        for (int k = 0; k < wv; ++k) add += wtot[k];
        if (idx < nloc) excl[idx] = add + inc - v;
        carry += wtot[0] + wtot[1] + wtot[2] + wtot[3];
    }
    __syncthreads();

    // row_start + dinv (coalesced writes; deg == hist)
    for (int i = t; i < nloc; i += 256) {
        row_start[nodebase + i] = beg + excl[i];
        dinv[nodebase + i] = rsqrtf((float)hist[i] + 1.0f);   // +1 self loop
    }
    if (b == nbkt - 1 && t == 0) row_start[n] = e;
    __syncthreads();
    for (int i = t; i < nloc; i += 256) hist[i] = 0;   // reuse as cursors
    __syncthreads();

    // fine scatter within bucket window (single XCD L2 locality)
    for (int i = beg + t; i < end; i += 256) {
        unsigned int u = bpack[i];
        int dl = (int)(u >> 16) - nodebase;
        int p = beg + excl[dl] + atomicAdd(&hist[dl], 1);
        csr_src[p] = (int)(u & 0xFFFFu);
    }
}

// ---------------- GEMM1: h1s = dinv[row] * (X @ W1)  (N x 64) ----------------
__global__ void k_gemm1(const float* __restrict__ X, const float* __restrict__ W1,
                        const float* __restrict__ dinv, float* __restrict__ h1s, int n) {
    __shared__ float xt[C_IN][64];
    __shared__ float wl[C_IN * C_HID];
    const int t = threadIdx.x;
    const int row0 = blockIdx.x * 64;

    for (int i = t; i < C_IN * C_HID; i += 256) wl[i] = W1[i];
    {
        int r = t >> 2, q = t & 3;
        int grow = row0 + r;
        for (int j = 0; j < 8; ++j) {
            int k = q * 32 + j * 4;
            float4 v = make_float4(0.f, 0.f, 0.f, 0.f);
            if (grow < n) v = *(const float4*)(X + (size_t)grow * C_IN + k);
            xt[k + 0][r] = v.x; xt[k + 1][r] = v.y; xt[k + 2][r] = v.z; xt[k + 3][r] = v.w;
        }
    }
    __syncthreads();

    const int rg = t >> 4, cg = t & 15;
    const int r0 = rg * 4, c0 = cg * 4;
    float acc[4][4] = {};
#pragma unroll 4
    for (int k = 0; k < C_IN; ++k) {
        float4 a = *(const float4*)&xt[k][r0];
        float4 b = *(const float4*)&wl[k * C_HID + c0];
        acc[0][0] = fmaf(a.x, b.x, acc[0][0]); acc[0][1] = fmaf(a.x, b.y, acc[0][1]);
        acc[0][2] = fmaf(a.x, b.z, acc[0][2]); acc[0][3] = fmaf(a.x, b.w, acc[0][3]);
        acc[1][0] = fmaf(a.y, b.x, acc[1][0]); acc[1][1] = fmaf(a.y, b.y, acc[1][1]);
        acc[1][2] = fmaf(a.y, b.z, acc[1][2]); acc[1][3] = fmaf(a.y, b.w, acc[1][3]);
        acc[2][0] = fmaf(a.z, b.x, acc[2][0]); acc[2][1] = fmaf(a.z, b.y, acc[2][1]);
        acc[2][2] = fmaf(a.z, b.z, acc[2][2]); acc[2][3] = fmaf(a.z, b.w, acc[2][3]);
        acc[3][0] = fmaf(a.w, b.x, acc[3][0]); acc[3][1] = fmaf(a.w, b.y, acc[3][1]);
        acc[3][2] = fmaf(a.w, b.z, acc[3][2]); acc[3][3] = fmaf(a.w, b.w, acc[3][3]);
    }
#pragma unroll
    for (int i = 0; i < 4; ++i) {
        int row = row0 + r0 + i;
        if (row < n) {
            float di = dinv[row];
            float4 o = make_float4(di * acc[i][0], di * acc[i][1], di * acc[i][2], di * acc[i][3]);
            *(float4*)(h1s + (size_t)row * C_HID + c0) = o;
        }
    }
}

// ---------------- layer-1 gather-aggregate + bias + relu ----------------
__global__ void k_agg1(const int* __restrict__ row_start, const int* __restrict__ csr_src,
                       const float* __restrict__ h1s, const float* __restrict__ dinv,
                       const float* __restrict__ b1, float* __restrict__ out1, int n) {
    int node = (blockIdx.x * 256 + threadIdx.x) >> 6;
    int lane = threadIdx.x & 63;
    if (node >= n) return;
    int beg = row_start[node], end = row_start[node + 1];
    float a0 = h1s[(size_t)node * C_HID + lane];
    float a1 = 0.f, a2 = 0.f, a3 = 0.f;
    for (int j = beg; j < end; j += 64) {
        int sv = (j + lane < end) ? csr_src[j + lane] : 0;
        int m = min(64, end - j);
        int k = 0;
        for (; k + 4 <= m; k += 4) {
            int s0 = __shfl(sv, k),     s1 = __shfl(sv, k + 1);
            int s2 = __shfl(sv, k + 2), s3 = __shfl(sv, k + 3);
            a0 += h1s[(size_t)s0 * C_HID + lane];
            a1 += h1s[(size_t)s1 * C_HID + lane];
            a2 += h1s[(size_t)s2 * C_HID + lane];
            a3 += h1s[(size_t)s3 * C_HID + lane];
        }
        for (; k < m; ++k) {
            int s = __shfl(sv, k);
            a0 += h1s[(size_t)s * C_HID + lane];
        }
    }
    float acc = (a0 + a1) + (a2 + a3);
    float v = dinv[node] * acc + b1[lane];
    out1[(size_t)node * C_HID + lane] = v > 0.f ? v : 0.f;
}

// ---------------- GEMM2: h2s = dinv[row] * (out1 @ W2)  (N x 40) ----------------
__global__ void k_gemm2(const float* __restrict__ X2, const float* __restrict__ W2,
                        const float* __restrict__ dinv, float* __restrict__ h2s, int n) {
    __shared__ float xt[C_HID][96];
    __shared__ float wl[C_HID * C_OUT];
    const int t = threadIdx.x;
    const int row0 = blockIdx.x * 96;

    for (int i = t; i < C_HID * C_OUT; i += 256) wl[i] = W2[i];
    for (int idx = t; idx < 96 * 16; idx += 256) {
        int r = idx >> 4, f4 = idx & 15;
        int grow = row0 + r;
        float4 v = make_float4(0.f, 0.f, 0.f, 0.f);
        if (grow < n) v = *(const float4*)(X2 + (size_t)grow * C_HID + f4 * 4);
        int k = f4 * 4;
        xt[k + 0][r] = v.x; xt[k + 1][r] = v.y; xt[k + 2][r] = v.z; xt[k + 3][r] = v.w;
    }
    __syncthreads();

    if (t >= 240) return;
    const int rg = t / 10, cg = t - rg * 10;   // 24 x 10
    const int r0 = rg * 4, c0 = cg * 4;
    float acc[4][4] = {};
#pragma unroll 4
    for (int k = 0; k < C_HID; ++k) {
        float4 a = *(const float4*)&xt[k][r0];
        float4 b = *(const float4*)&wl[k * C_OUT + c0];
        acc[0][0] = fmaf(a.x, b.x, acc[0][0]); acc[0][1] = fmaf(a.x, b.y, acc[0][1]);
        acc[0][2] = fmaf(a.x, b.z, acc[0][2]); acc[0][3] = fmaf(a.x, b.w, acc[0][3]);
        acc[1][0] = fmaf(a.y, b.x, acc[1][0]); acc[1][1] = fmaf(a.y, b.y, acc[1][1]);
        acc[1][2] = fmaf(a.y, b.z, acc[1][2]); acc[1][3] = fmaf(a.y, b.w, acc[1][3]);
        acc[2][0] = fmaf(a.z, b.x, acc[2][0]); acc[2][1] = fmaf(a.z, b.y, acc[2][1]);
        acc[2][2] = fmaf(a.z, b.z, acc[2][2]); acc[2][3] = fmaf(a.z, b.w, acc[2][3]);
        acc[3][0] = fmaf(a.w, b.x, acc[3][0]); acc[3][1] = fmaf(a.w, b.y, acc[3][1]);
        acc[3][2] = fmaf(a.w, b.z, acc[3][2]); acc[3][3] = fmaf(a.w, b.w, acc[3][3]);
    }
#pragma unroll
    for (int i = 0; i < 4; ++i) {
        int row = row0 + r0 + i;
        if (row < n) {
            float di = dinv[row];
            float4 o = make_float4(di * acc[i][0], di * acc[i][1], di * acc[i][2], di * acc[i][3]);
            *(float4*)(h2s + (size_t)row * C_OUT + c0) = o;
        }
    }
}

// ---------------- layer-2 gather-aggregate + bias + log_softmax ----------------
__global__ void k_agg2(const int* __restrict__ row_start, const int* __restrict__ csr_src,
                       const float* __restrict__ h2s, const float* __restrict__ dinv,
                       const float* __restrict__ b2, float* __restrict__ out, int n) {
    int node = (blockIdx.x * 256 + threadIdx.x) >> 6;
    int lane = threadIdx.x & 63;
    if (node >= n) return;
    int beg = row_start[node], end = row_start[node + 1];
    float a0 = (lane < C_OUT) ? h2s[(size_t)node * C_OUT + lane] : 0.f;
    float a1 = 0.f, a2 = 0.f, a3 = 0.f;
    for (int j = beg; j < end; j += 64) {
        int sv = (j + lane < end) ? csr_src[j + lane] : 0;
        int m = min(64, end - j);
        int k = 0;
        for (; k + 4 <= m; k += 4) {
            int s0 = __shfl(sv, k),     s1 = __shfl(sv, k + 1);
            int s2 = __shfl(sv, k + 2), s3 = __shfl(sv, k + 3);
            if (lane < C_OUT) {
                a0 += h2s[(size_t)s0 * C_OUT + lane];
                a1 += h2s[(size_t)s1 * C_OUT + lane];
                a2 += h2s[(size_t)s2 * C_OUT + lane];
                a3 += h2s[(size_t)s3 * C_OUT + lane];
            }
        }
        for (; k < m; ++k) {
            int s = __shfl(sv, k);
            if (lane < C_OUT) a0 += h2s[(size_t)s * C_OUT + lane];
        }
    }
    float acc = (a0 + a1) + (a2 + a3);
    float v = (lane < C_OUT) ? dinv[node] * acc + b2[lane] : -INFINITY;
    float mx = v;
    for (int off = 32; off; off >>= 1) mx = fmaxf(mx, __shfl_xor(mx, off));
    float ex = (lane < C_OUT) ? expf(v - mx) : 0.f;
    float ss = ex;
    for (int off = 32; off; off >>= 1) ss += __shfl_xor(ss, off);
    float lse = mx + logf(ss);
    if (lane < C_OUT) out[(size_t)node * C_OUT + lane] = v - lse;
}

extern "C" void kernel_launch(void* const* d_in, const int* in_sizes, int n_in,
                              void* d_out, int out_size, void* d_ws, size_t ws_size,
                              hipStream_t stream) {
    const float* X   = (const float*)d_in[0];
    const int*   src = (const int*)d_in[1];
    const int*   dst = (const int*)d_in[2];
    const float* W1  = (const float*)d_in[3];
    const float* b1  = (const float*)d_in[4];
    const float* W2  = (const float*)d_in[5];
    const float* b2  = (const float*)d_in[6];
    float* out = (float*)d_out;

    const int N = in_sizes[0] / C_IN;
    const int E = in_sizes[1];
    const int NBKT = (N + BKT_N - 1) >> BKT_SH;
    const int nchunks = (E + CHUNK - 1) / CHUNK;

    // workspace layout
    char* ws = (char*)d_ws;
    size_t off = 0;
    auto take = [&](size_t bytes) { char* p = ws + off; off = (off + bytes + 255) & ~(size_t)255; return p; };
    int*   tot       = (int*)  take(256 * 4);
    int*   bstart    = (int*)  take(257 * 4);
    int*   bcur      = (int*)  take(256 * 4);
    unsigned int* bpack = (unsigned int*)take((size_t)E * 4);
    int*   csr_src   = (int*)  take((size_t)E * 4);
    int*   row_start = (int*)  take((size_t)(N + 1) * 4);
    float* dinv      = (float*)take((size_t)N * 4);
    float* h1s       = (float*)take((size_t)N * C_HID * 4);
    float* out1      = (float*)take((size_t)N * C_HID * 4);
    float* h2s       = h1s;  // h1s dead after k_agg1

    hipMemsetAsync(tot, 0, (size_t)NBKT * 4, stream);
    k_hist    <<<nchunks, 256, 0, stream>>>(dst, tot, E, NBKT);
    k_scan_bkt<<<1, 256, 0, stream>>>(tot, bstart, bcur, NBKT, E);
    k_binA    <<<nchunks, 256, 0, stream>>>(src, dst, bcur, bpack, E, NBKT);
    k_binB    <<<NBKT, 256, 0, stream>>>(bstart, bpack, row_start, dinv, csr_src, N, E, NBKT);

    k_gemm1   <<<(N + 63) / 64, 256, 0, stream>>>(X, W1, dinv, h1s, N);
    k_agg1    <<<((size_t)N * 64 + 255) / 256, 256, 0, stream>>>(row_start, csr_src, h1s, dinv, b1, out1, N);

    k_gemm2   <<<(N + 95) / 96, 256, 0, stream>>>(out1, W2, dinv, h2s, N);
    k_agg2    <<<((size_t)N * 64 + 255) / 256, 256, 0, stream>>>(row_start, csr_src, h2s, dinv, b2, out, N);
}

// Round 6
// 147.924 us; speedup vs baseline: 2.0834x; 1.0744x over previous
//
#include <hip/hip_runtime.h>
#include <math.h>

#define C_IN  128
#define C_HID 64
#define C_OUT 40

#define BKT_SH 9
#define BKT_N  (1 << BKT_SH)          // 512 nodes per bucket
#define CHUNK  4096                   // edges per hist/binA block
#define EPT    (CHUNK / 256)          // 16 edges per thread
// NOTE: nchunks (=196 for E=800k) must be <= 256 for k_bktscan's one-pass scan.

// ---------------- pass 0: per-chunk, per-bucket histogram (no global atomics) ----------------
__global__ void k_hist(const int* __restrict__ dst, int* __restrict__ hist2d, int e, int nbkt) {
    __shared__ int hist[256];
    for (int i = threadIdx.x; i < nbkt; i += 256) hist[i] = 0;
    __syncthreads();
    int base = blockIdx.x * CHUNK;
#pragma unroll
    for (int j = 0; j < EPT; ++j) {
        int i = base + j * 256 + threadIdx.x;
        if (i < e) atomicAdd(&hist[dst[i] >> BKT_SH], 1);
    }
    __syncthreads();
    int* row = hist2d + (size_t)blockIdx.x * nbkt;
    for (int i = threadIdx.x; i < nbkt; i += 256) row[i] = hist[i];
}

// ---------------- per-bucket scan over chunks: base2d + tot ----------------
__global__ void k_bktscan(const int* __restrict__ hist2d, int* __restrict__ base2d,
                          int* __restrict__ tot, int nchunks, int nbkt) {
    __shared__ int wtot[4];
    const int b = blockIdx.x;
    const int t = threadIdx.x;
    int v = (t < nchunks) ? hist2d[(size_t)t * nbkt + b] : 0;
    int lane = t & 63, wv = t >> 6;
    int inc = v;
    for (int o = 1; o < 64; o <<= 1) { int u = __shfl_up(inc, o); if (lane >= o) inc += u; }
    if (lane == 63) wtot[wv] = inc;
    __syncthreads();
    int add = 0;
    for (int k = 0; k < wv; ++k) add += wtot[k];
    if (t < nchunks) base2d[(size_t)t * nbkt + b] = add + inc - v;   // exclusive within bucket
    if (t == 255) tot[b] = add + inc;                                // bucket total
}

// ---------------- tiny parallel scan over bucket totals -> bstart ----------------
__global__ void k_scan_bkt(const int* __restrict__ tot, int* __restrict__ bstart, int nbkt, int e) {
    __shared__ int wtot[4];
    const int t = threadIdx.x;
    int v = (t < nbkt) ? tot[t] : 0;
    int lane = t & 63, wv = t >> 6;
    int inc = v;
    for (int o = 1; o < 64; o <<= 1) { int u = __shfl_up(inc, o); if (lane >= o) inc += u; }
    if (lane == 63) wtot[wv] = inc;
    __syncthreads();
    int add = 0;
    for (int k = 0; k < wv; ++k) add += wtot[k];
    if (t < nbkt) bstart[t] = add + inc - v;
    if (t == 0) bstart[nbkt] = e;
}

// ---------------- pass A: LDS multisplit by bucket, coalesced flush (no global atomics) ----------------
__global__ void k_binA(const int* __restrict__ src, const int* __restrict__ dst,
                       const int* __restrict__ bstart, const int* __restrict__ base2d,
                       unsigned int* __restrict__ bpack, int e, int nbkt) {
    __shared__ int hist[256];          // histogram, then local cursors
    __shared__ int excl[256];
    __shared__ int gbase[256];
    __shared__ int wtot[4];
    __shared__ unsigned int stage[CHUNK];
    const int t = threadIdx.x;
    const int base = blockIdx.x * CHUNK;

    for (int i = t; i < nbkt; i += 256) hist[i] = 0;
    __syncthreads();

    unsigned int pk[EPT]; int bk[EPT];
#pragma unroll
    for (int j = 0; j < EPT; ++j) {
        int i = base + j * 256 + t;
        if (i < e) {
            int d = dst[i];
            pk[j] = (unsigned int)src[i] | ((unsigned int)d << 16);   // N < 65536
            bk[j] = d >> BKT_SH;
            atomicAdd(&hist[bk[j]], 1);
        } else bk[j] = -1;
    }
    __syncthreads();

    // parallel exclusive scan of hist[0..nbkt) (nbkt <= 256)
    {
        int lane = t & 63, wv = t >> 6;
        int v = (t < nbkt) ? hist[t] : 0;
        int inc = v;
        for (int o = 1; o < 64; o <<= 1) { int u = __shfl_up(inc, o); if (lane >= o) inc += u; }
        if (lane == 63) wtot[wv] = inc;
        __syncthreads();
        int add = 0;
        for (int k = 0; k < wv; ++k) add += wtot[k];
        if (t < nbkt) excl[t] = add + inc - v;
    }
    __syncthreads();

    // global base per bucket: precomputed, deterministic
    for (int i = t; i < nbkt; i += 256)
        gbase[i] = bstart[i] + base2d[(size_t)blockIdx.x * nbkt + i];
    __syncthreads();
    for (int i = t; i < nbkt; i += 256) hist[i] = 0;   // reuse as local cursors
    __syncthreads();

    // LDS scatter into bucket-sorted order
#pragma unroll
    for (int j = 0; j < EPT; ++j) {
        if (bk[j] >= 0) {
            int p = excl[bk[j]] + atomicAdd(&hist[bk[j]], 1);
            stage[p] = pk[j];
        }
    }
    __syncthreads();

    // coalesced flush: consecutive LDS slots in a bucket -> consecutive global
    int nchunk = min(CHUNK, e - base);
    for (int i = t; i < nchunk; i += 256) {
        unsigned int u = stage[i];
        int b = (int)(u >> 16) >> BKT_SH;
        bpack[gbase[b] + (i - excl[b])] = u;
    }
}

// ---------------- pass B: per-bucket counting sort -> deg/dinv/row_start/csr_src ----------------
__global__ void k_binB(const int* __restrict__ bstart, const unsigned int* __restrict__ bpack,
                       int* __restrict__ row_start, float* __restrict__ dinv,
                       int* __restrict__ csr_src, int n, int e, int nbkt) {
    __shared__ int hist[BKT_N];
    __shared__ int excl[BKT_N];
    __shared__ int wtot[4];
    const int t = threadIdx.x;
    const int b = blockIdx.x;
    const int beg = bstart[b], end = bstart[b + 1];
    const int nodebase = b << BKT_SH;
    const int nloc = min(BKT_N, n - nodebase);

    for (int i = t; i < nloc; i += 256) hist[i] = 0;
    __syncthreads();
    for (int i = beg + t; i < end; i += 256)
        atomicAdd(&hist[(int)(bpack[i] >> 16) - nodebase], 1);
    __syncthreads();

    // exclusive scan of hist[0..nloc) in 256-wide passes with carry
    int carry = 0;
    for (int base0 = 0; base0 < nloc; base0 += 256) {
        __syncthreads();
        int idx = base0 + t;
        int v = (idx < nloc) ? hist[idx] : 0;
        int inc = v; int lane = t & 63; int wv = t >> 6;
        for (int o = 1; o < 64; o <<= 1) { int u = __shfl_up(inc, o); if (lane >= o) inc += u; }
        if (lane == 63) wtot[wv] = inc;
        __syncthreads();
        int add = carry;
        for (int k = 0; k < wv; ++k) add += wtot[k];
        if (idx < nloc) excl[idx] = add + inc - v;
        carry += wtot[0] + wtot[1] + wtot[2] + wtot[3];
    }
    __syncthreads();

    // row_start + dinv (coalesced writes; deg == hist)
    for (int i = t; i < nloc; i += 256) {
        row_start[nodebase + i] = beg + excl[i];
        dinv[nodebase + i] = rsqrtf((float)hist[i] + 1.0f);   // +1 self loop
    }
    if (b == nbkt - 1 && t == 0) row_start[n] = e;
    __syncthreads();
    for (int i = t; i < nloc; i += 256) hist[i] = 0;   // reuse as cursors
    __syncthreads();

    // fine scatter within bucket window (single XCD L2 locality)
    for (int i = beg + t; i < end; i += 256) {
        unsigned int u = bpack[i];
        int dl = (int)(u >> 16) - nodebase;
        int p = beg + excl[dl] + atomicAdd(&hist[dl], 1);
        csr_src[p] = (int)(u & 0xFFFFu);
    }
}

// ---------------- GEMM1: h1s = dinv[row] * (X @ W1)  (N x 64) ----------------
__global__ void k_gemm1(const float* __restrict__ X, const float* __restrict__ W1,
                        const float* __restrict__ dinv, float* __restrict__ h1s, int n) {
    __shared__ float xt[C_IN][64];
    __shared__ float wl[C_IN * C_HID];
    const int t = threadIdx.x;
    const int row0 = blockIdx.x * 64;

    for (int i = t; i < C_IN * C_HID; i += 256) wl[i] = W1[i];
    {
        int r = t >> 2, q = t & 3;
        int grow = row0 + r;
        for (int j = 0; j < 8; ++j) {
            int k = q * 32 + j * 4;
            float4 v = make_float4(0.f, 0.f, 0.f, 0.f);
            if (grow < n) v = *(const float4*)(X + (size_t)grow * C_IN + k);
            xt[k + 0][r] = v.x; xt[k + 1][r] = v.y; xt[k + 2][r] = v.z; xt[k + 3][r] = v.w;
        }
    }
    __syncthreads();

    const int rg = t >> 4, cg = t & 15;
    const int r0 = rg * 4, c0 = cg * 4;
    float acc[4][4] = {};
#pragma unroll 4
    for (int k = 0; k < C_IN; ++k) {
        float4 a = *(const float4*)&xt[k][r0];
        float4 b = *(const float4*)&wl[k * C_HID + c0];
        acc[0][0] = fmaf(a.x, b.x, acc[0][0]); acc[0][1] = fmaf(a.x, b.y, acc[0][1]);
        acc[0][2] = fmaf(a.x, b.z, acc[0][2]); acc[0][3] = fmaf(a.x, b.w, acc[0][3]);
        acc[1][0] = fmaf(a.y, b.x, acc[1][0]); acc[1][1] = fmaf(a.y, b.y, acc[1][1]);
        acc[1][2] = fmaf(a.y, b.z, acc[1][2]); acc[1][3] = fmaf(a.y, b.w, acc[1][3]);
        acc[2][0] = fmaf(a.z, b.x, acc[2][0]); acc[2][1] = fmaf(a.z, b.y, acc[2][1]);
        acc[2][2] = fmaf(a.z, b.z, acc[2][2]); acc[2][3] = fmaf(a.z, b.w, acc[2][3]);
        acc[3][0] = fmaf(a.w, b.x, acc[3][0]); acc[3][1] = fmaf(a.w, b.y, acc[3][1]);
        acc[3][2] = fmaf(a.w, b.z, acc[3][2]); acc[3][3] = fmaf(a.w, b.w, acc[3][3]);
    }
#pragma unroll
    for (int i = 0; i < 4; ++i) {
        int row = row0 + r0 + i;
        if (row < n) {
            float di = dinv[row];
            float4 o = make_float4(di * acc[i][0], di * acc[i][1], di * acc[i][2], di * acc[i][3]);
            *(float4*)(h1s + (size_t)row * C_HID + c0) = o;
        }
    }
}

// ---------------- layer-1 gather-aggregate + bias + relu ----------------
__global__ void k_agg1(const int* __restrict__ row_start, const int* __restrict__ csr_src,
                       const float* __restrict__ h1s, const float* __restrict__ dinv,
                       const float* __restrict__ b1, float* __restrict__ out1, int n) {
    int node = (blockIdx.x * 256 + threadIdx.x) >> 6;
    int lane = threadIdx.x & 63;
    if (node >= n) return;
    int beg = row_start[node], end = row_start[node + 1];
    float a0 = h1s[(size_t)node * C_HID + lane];
    float a1 = 0.f, a2 = 0.f, a3 = 0.f;
    for (int j = beg; j < end; j += 64) {
        int sv = (j + lane < end) ? csr_src[j + lane] : 0;
        int m = min(64, end - j);
        int k = 0;
        for (; k + 4 <= m; k += 4) {
            int s0 = __shfl(sv, k),     s1 = __shfl(sv, k + 1);
            int s2 = __shfl(sv, k + 2), s3 = __shfl(sv, k + 3);
            a0 += h1s[(size_t)s0 * C_HID + lane];
            a1 += h1s[(size_t)s1 * C_HID + lane];
            a2 += h1s[(size_t)s2 * C_HID + lane];
            a3 += h1s[(size_t)s3 * C_HID + lane];
        }
        for (; k < m; ++k) {
            int s = __shfl(sv, k);
            a0 += h1s[(size_t)s * C_HID + lane];
        }
    }
    float acc = (a0 + a1) + (a2 + a3);
    float v = dinv[node] * acc + b1[lane];
    out1[(size_t)node * C_HID + lane] = v > 0.f ? v : 0.f;
}

// ---------------- GEMM2: h2s = dinv[row] * (out1 @ W2)  (N x 40) ----------------
__global__ void k_gemm2(const float* __restrict__ X2, const float* __restrict__ W2,
                        const float* __restrict__ dinv, float* __restrict__ h2s, int n) {
    __shared__ float xt[C_HID][96];
    __shared__ float wl[C_HID * C_OUT];
    const int t = threadIdx.x;
    const int row0 = blockIdx.x * 96;

    for (int i = t; i < C_HID * C_OUT; i += 256) wl[i] = W2[i];
    for (int idx = t; idx < 96 * 16; idx += 256) {
        int r = idx >> 4, f4 = idx & 15;
        int grow = row0 + r;
        float4 v = make_float4(0.f, 0.f, 0.f, 0.f);
        if (grow < n) v = *(const float4*)(X2 + (size_t)grow * C_HID + f4 * 4);
        int k = f4 * 4;
        xt[k + 0][r] = v.x; xt[k + 1][r] = v.y; xt[k + 2][r] = v.z; xt[k + 3][r] = v.w;
    }
    __syncthreads();

    if (t >= 240) return;
    const int rg = t / 10, cg = t - rg * 10;   // 24 x 10
    const int r0 = rg * 4, c0 = cg * 4;
    float acc[4][4] = {};
#pragma unroll 4
    for (int k = 0; k < C_HID; ++k) {
        float4 a = *(const float4*)&xt[k][r0];
        float4 b = *(const float4*)&wl[k * C_OUT + c0];
        acc[0][0] = fmaf(a.x, b.x, acc[0][0]); acc[0][1] = fmaf(a.x, b.y, acc[0][1]);
        acc[0][2] = fmaf(a.x, b.z, acc[0][2]); acc[0][3] = fmaf(a.x, b.w, acc[0][3]);
        acc[1][0] = fmaf(a.y, b.x, acc[1][0]); acc[1][1] = fmaf(a.y, b.y, acc[1][1]);
        acc[1][2] = fmaf(a.y, b.z, acc[1][2]); acc[1][3] = fmaf(a.y, b.w, acc[1][3]);
        acc[2][0] = fmaf(a.z, b.x, acc[2][0]); acc[2][1] = fmaf(a.z, b.y, acc[2][1]);
        acc[2][2] = fmaf(a.z, b.z, acc[2][2]); acc[2][3] = fmaf(a.z, b.w, acc[2][3]);
        acc[3][0] = fmaf(a.w, b.x, acc[3][0]); acc[3][1] = fmaf(a.w, b.y, acc[3][1]);
        acc[3][2] = fmaf(a.w, b.z, acc[3][2]); acc[3][3] = fmaf(a.w, b.w, acc[3][3]);
    }
#pragma unroll
    for (int i = 0; i < 4; ++i) {
        int row = row0 + r0 + i;
        if (row < n) {
            float di = dinv[row];
            float4 o = make_float4(di * acc[i][0], di * acc[i][1], di * acc[i][2], di * acc[i][3]);
            *(float4*)(h2s + (size_t)row * C_OUT + c0) = o;
        }
    }
}

// ---------------- layer-2 gather-aggregate + bias + log_softmax ----------------
__global__ void k_agg2(const int* __restrict__ row_start, const int* __restrict__ csr_src,
                       const float* __restrict__ h2s, const float* __restrict__ dinv,
                       const float* __restrict__ b2, float* __restrict__ out, int n) {
    int node = (blockIdx.x * 256 + threadIdx.x) >> 6;
    int lane = threadIdx.x & 63;
    if (node >= n) return;
    int beg = row_start[node], end = row_start[node + 1];
    float a0 = (lane < C_OUT) ? h2s[(size_t)node * C_OUT + lane] : 0.f;
    float a1 = 0.f, a2 = 0.f, a3 = 0.f;
    for (int j = beg; j < end; j += 64) {
        int sv = (j + lane < end) ? csr_src[j + lane] : 0;
        int m = min(64, end - j);
        int k = 0;
        for (; k + 4 <= m; k += 4) {
            int s0 = __shfl(sv, k),     s1 = __shfl(sv, k + 1);
            int s2 = __shfl(sv, k + 2), s3 = __shfl(sv, k + 3);
            if (lane < C_OUT) {
                a0 += h2s[(size_t)s0 * C_OUT + lane];
                a1 += h2s[(size_t)s1 * C_OUT + lane];
                a2 += h2s[(size_t)s2 * C_OUT + lane];
                a3 += h2s[(size_t)s3 * C_OUT + lane];
            }
        }
        for (; k < m; ++k) {
            int s = __shfl(sv, k);
            if (lane < C_OUT) a0 += h2s[(size_t)s * C_OUT + lane];
        }
    }
    float acc = (a0 + a1) + (a2 + a3);
    float v = (lane < C_OUT) ? dinv[node] * acc + b2[lane] : -INFINITY;
    float mx = v;
    for (int off = 32; off; off >>= 1) mx = fmaxf(mx, __shfl_xor(mx, off));
    float ex = (lane < C_OUT) ? expf(v - mx) : 0.f;
    float ss = ex;
    for (int off = 32; off; off >>= 1) ss += __shfl_xor(ss, off);
    float lse = mx + logf(ss);
    if (lane < C_OUT) out[(size_t)node * C_OUT + lane] = v - lse;
}

extern "C" void kernel_launch(void* const* d_in, const int* in_sizes, int n_in,
                              void* d_out, int out_size, void* d_ws, size_t ws_size,
                              hipStream_t stream) {
    const float* X   = (const float*)d_in[0];
    const int*   src = (const int*)d_in[1];
    const int*   dst = (const int*)d_in[2];
    const float* W1  = (const float*)d_in[3];
    const float* b1  = (const float*)d_in[4];
    const float* W2  = (const float*)d_in[5];
    const float* b2  = (const float*)d_in[6];
    float* out = (float*)d_out;

    const int N = in_sizes[0] / C_IN;
    const int E = in_sizes[1];
    const int NBKT = (N + BKT_N - 1) >> BKT_SH;
    const int nchunks = (E + CHUNK - 1) / CHUNK;   // must be <= 256

    // workspace layout
    char* ws = (char*)d_ws;
    size_t off = 0;
    auto take = [&](size_t bytes) { char* p = ws + off; off = (off + bytes + 255) & ~(size_t)255; return p; };
    int*   hist2d    = (int*)  take((size_t)nchunks * NBKT * 4);
    int*   base2d    = (int*)  take((size_t)nchunks * NBKT * 4);
    int*   tot       = (int*)  take(256 * 4);
    int*   bstart    = (int*)  take(257 * 4);
    unsigned int* bpack = (unsigned int*)take((size_t)E * 4);
    int*   csr_src   = (int*)  take((size_t)E * 4);
    int*   row_start = (int*)  take((size_t)(N + 1) * 4);
    float* dinv      = (float*)take((size_t)N * 4);
    float* h1s       = (float*)take((size_t)N * C_HID * 4);
    float* out1      = (float*)take((size_t)N * C_HID * 4);
    float* h2s       = h1s;  // h1s dead after k_agg1

    k_hist    <<<nchunks, 256, 0, stream>>>(dst, hist2d, E, NBKT);
    k_bktscan <<<NBKT, 256, 0, stream>>>(hist2d, base2d, tot, nchunks, NBKT);
    k_scan_bkt<<<1, 256, 0, stream>>>(tot, bstart, NBKT, E);
    k_binA    <<<nchunks, 256, 0, stream>>>(src, dst, bstart, base2d, bpack, E, NBKT);
    k_binB    <<<NBKT, 256, 0, stream>>>(bstart, bpack, row_start, dinv, csr_src, N, E, NBKT);

    k_gemm1   <<<(N + 63) / 64, 256, 0, stream>>>(X, W1, dinv, h1s, N);
    k_agg1    <<<((size_t)N * 64 + 255) / 256, 256, 0, stream>>>(row_start, csr_src, h1s, dinv, b1, out1, N);

    k_gemm2   <<<(N + 95) / 96, 256, 0, stream>>>(out1, W2, dinv, h2s, N);
    k_agg2    <<<((size_t)N * 64 + 255) / 256, 256, 0, stream>>>(row_start, csr_src, h2s, dinv, b2, out, N);
}

// Round 7
// 146.794 us; speedup vs baseline: 2.0995x; 1.0077x over previous
//
#include <hip/hip_runtime.h>
#include <math.h>

#define C_IN  128
#define C_HID 64
#define C_OUT 40

#define BKT_SH 9
#define BKT_N  (1 << BKT_SH)          // 512 nodes per bucket
#define CHUNK  4096                   // edges per hist/binA block
#define EPT    (CHUNK / 256)          // 16 edges per thread
// NOTE: nchunks (=196 for E=800k) must be <= 256 for k_bktscan's one-pass scan.

// ---------------- pass 0: per-chunk, per-bucket histogram (no global atomics) ----------------
__global__ void k_hist(const int* __restrict__ dst, int* __restrict__ hist2d, int e, int nbkt) {
    __shared__ int hist[256];
    for (int i = threadIdx.x; i < nbkt; i += 256) hist[i] = 0;
    __syncthreads();
    int base = blockIdx.x * CHUNK;
#pragma unroll
    for (int j = 0; j < EPT; ++j) {
        int i = base + j * 256 + threadIdx.x;
        if (i < e) atomicAdd(&hist[dst[i] >> BKT_SH], 1);
    }
    __syncthreads();
    int* row = hist2d + (size_t)blockIdx.x * nbkt;
    for (int i = threadIdx.x; i < nbkt; i += 256) row[i] = hist[i];
}

// ---------------- per-bucket scan over chunks: base2d + tot ----------------
__global__ void k_bktscan(const int* __restrict__ hist2d, int* __restrict__ base2d,
                          int* __restrict__ tot, int nchunks, int nbkt) {
    __shared__ int wtot[4];
    const int b = blockIdx.x;
    const int t = threadIdx.x;
    int v = (t < nchunks) ? hist2d[(size_t)t * nbkt + b] : 0;
    int lane = t & 63, wv = t >> 6;
    int inc = v;
    for (int o = 1; o < 64; o <<= 1) { int u = __shfl_up(inc, o); if (lane >= o) inc += u; }
    if (lane == 63) wtot[wv] = inc;
    __syncthreads();
    int add = 0;
    for (int k = 0; k < wv; ++k) add += wtot[k];
    if (t < nchunks) base2d[(size_t)t * nbkt + b] = add + inc - v;   // exclusive within bucket
    if (t == 255) tot[b] = add + inc;                                // bucket total
}

// ---------------- tiny parallel scan over bucket totals -> bstart ----------------
__global__ void k_scan_bkt(const int* __restrict__ tot, int* __restrict__ bstart, int nbkt, int e) {
    __shared__ int wtot[4];
    const int t = threadIdx.x;
    int v = (t < nbkt) ? tot[t] : 0;
    int lane = t & 63, wv = t >> 6;
    int inc = v;
    for (int o = 1; o < 64; o <<= 1) { int u = __shfl_up(inc, o); if (lane >= o) inc += u; }
    if (lane == 63) wtot[wv] = inc;
    __syncthreads();
    int add = 0;
    for (int k = 0; k < wv; ++k) add += wtot[k];
    if (t < nbkt) bstart[t] = add + inc - v;
    if (t == 0) bstart[nbkt] = e;
}

// ---------------- pass A: LDS multisplit by bucket, coalesced flush (no global atomics) ----------------
__global__ void k_binA(const int* __restrict__ src, const int* __restrict__ dst,
                       const int* __restrict__ bstart, const int* __restrict__ base2d,
                       unsigned int* __restrict__ bpack, int e, int nbkt) {
    __shared__ int hist[256];          // histogram, then local cursors
    __shared__ int excl[256];
    __shared__ int gbase[256];
    __shared__ int wtot[4];
    __shared__ unsigned int stage[CHUNK];
    const int t = threadIdx.x;
    const int base = blockIdx.x * CHUNK;

    for (int i = t; i < nbkt; i += 256) hist[i] = 0;
    __syncthreads();

    unsigned int pk[EPT]; int bk[EPT];
#pragma unroll
    for (int j = 0; j < EPT; ++j) {
        int i = base + j * 256 + t;
        if (i < e) {
            int d = dst[i];
            pk[j] = (unsigned int)src[i] | ((unsigned int)d << 16);   // N < 65536
            bk[j] = d >> BKT_SH;
            atomicAdd(&hist[bk[j]], 1);
        } else bk[j] = -1;
    }
    __syncthreads();

    // parallel exclusive scan of hist[0..nbkt) (nbkt <= 256)
    {
        int lane = t & 63, wv = t >> 6;
        int v = (t < nbkt) ? hist[t] : 0;
        int inc = v;
        for (int o = 1; o < 64; o <<= 1) { int u = __shfl_up(inc, o); if (lane >= o) inc += u; }
        if (lane == 63) wtot[wv] = inc;
        __syncthreads();
        int add = 0;
        for (int k = 0; k < wv; ++k) add += wtot[k];
        if (t < nbkt) excl[t] = add + inc - v;
    }
    __syncthreads();

    // global base per bucket: precomputed, deterministic
    for (int i = t; i < nbkt; i += 256)
        gbase[i] = bstart[i] + base2d[(size_t)blockIdx.x * nbkt + i];
    __syncthreads();
    for (int i = t; i < nbkt; i += 256) hist[i] = 0;   // reuse as local cursors
    __syncthreads();

    // LDS scatter into bucket-sorted order
#pragma unroll
    for (int j = 0; j < EPT; ++j) {
        if (bk[j] >= 0) {
            int p = excl[bk[j]] + atomicAdd(&hist[bk[j]], 1);
            stage[p] = pk[j];
        }
    }
    __syncthreads();

    // coalesced flush: consecutive LDS slots in a bucket -> consecutive global
    int nchunk = min(CHUNK, e - base);
    for (int i = t; i < nchunk; i += 256) {
        unsigned int u = stage[i];
        int b = (int)(u >> 16) >> BKT_SH;
        bpack[gbase[b] + (i - excl[b])] = u;
    }
}

// ---------------- pass B: per-bucket counting sort -> deg/dinv/row_start/csr_src ----------------
__global__ void k_binB(const int* __restrict__ bstart, const unsigned int* __restrict__ bpack,
                       int* __restrict__ row_start, float* __restrict__ dinv,
                       int* __restrict__ csr_src, int n, int e, int nbkt) {
    __shared__ int hist[BKT_N];
    __shared__ int excl[BKT_N];
    __shared__ int wtot[4];
    const int t = threadIdx.x;
    const int b = blockIdx.x;
    const int beg = bstart[b], end = bstart[b + 1];
    const int nodebase = b << BKT_SH;
    const int nloc = min(BKT_N, n - nodebase);

    for (int i = t; i < nloc; i += 256) hist[i] = 0;
    __syncthreads();
    for (int i = beg + t; i < end; i += 256)
        atomicAdd(&hist[(int)(bpack[i] >> 16) - nodebase], 1);
    __syncthreads();

    // exclusive scan of hist[0..nloc) in 256-wide passes with carry
    int carry = 0;
    for (int base0 = 0; base0 < nloc; base0 += 256) {
        __syncthreads();
        int idx = base0 + t;
        int v = (idx < nloc) ? hist[idx] : 0;
        int inc = v; int lane = t & 63; int wv = t >> 6;
        for (int o = 1; o < 64; o <<= 1) { int u = __shfl_up(inc, o); if (lane >= o) inc += u; }
        if (lane == 63) wtot[wv] = inc;
        __syncthreads();
        int add = carry;
        for (int k = 0; k < wv; ++k) add += wtot[k];
        if (idx < nloc) excl[idx] = add + inc - v;
        carry += wtot[0] + wtot[1] + wtot[2] + wtot[3];
    }
    __syncthreads();

    // row_start + dinv (coalesced writes; deg == hist)
    for (int i = t; i < nloc; i += 256) {
        row_start[nodebase + i] = beg + excl[i];
        dinv[nodebase + i] = rsqrtf((float)hist[i] + 1.0f);   // +1 self loop
    }
    if (b == nbkt - 1 && t == 0) row_start[n] = e;
    __syncthreads();
    for (int i = t; i < nloc; i += 256) hist[i] = 0;   // reuse as cursors
    __syncthreads();

    // fine scatter within bucket window (single XCD L2 locality)
    for (int i = beg + t; i < end; i += 256) {
        unsigned int u = bpack[i];
        int dl = (int)(u >> 16) - nodebase;
        int p = beg + excl[dl] + atomicAdd(&hist[dl], 1);
        csr_src[p] = (int)(u & 0xFFFFu);
    }
}

// ---------------- GEMM1: h1s = dinv[row] * (X @ W1)  (N x 64) ----------------
__global__ void k_gemm1(const float* __restrict__ X, const float* __restrict__ W1,
                        const float* __restrict__ dinv, float* __restrict__ h1s, int n) {
    __shared__ float xt[C_IN][64];
    __shared__ float wl[C_IN * C_HID];
    const int t = threadIdx.x;
    const int row0 = blockIdx.x * 64;

    for (int i = t; i < C_IN * C_HID; i += 256) wl[i] = W1[i];
    {
        int r = t >> 2, q = t & 3;
        int grow = row0 + r;
        for (int j = 0; j < 8; ++j) {
            int k = q * 32 + j * 4;
            float4 v = make_float4(0.f, 0.f, 0.f, 0.f);
            if (grow < n) v = *(const float4*)(X + (size_t)grow * C_IN + k);
            xt[k + 0][r] = v.x; xt[k + 1][r] = v.y; xt[k + 2][r] = v.z; xt[k + 3][r] = v.w;
        }
    }
    __syncthreads();

    const int rg = t >> 4, cg = t & 15;
    const int r0 = rg * 4, c0 = cg * 4;
    float acc[4][4] = {};
#pragma unroll 4
    for (int k = 0; k < C_IN; ++k) {
        float4 a = *(const float4*)&xt[k][r0];
        float4 b = *(const float4*)&wl[k * C_HID + c0];
        acc[0][0] = fmaf(a.x, b.x, acc[0][0]); acc[0][1] = fmaf(a.x, b.y, acc[0][1]);
        acc[0][2] = fmaf(a.x, b.z, acc[0][2]); acc[0][3] = fmaf(a.x, b.w, acc[0][3]);
        acc[1][0] = fmaf(a.y, b.x, acc[1][0]); acc[1][1] = fmaf(a.y, b.y, acc[1][1]);
        acc[1][2] = fmaf(a.y, b.z, acc[1][2]); acc[1][3] = fmaf(a.y, b.w, acc[1][3]);
        acc[2][0] = fmaf(a.z, b.x, acc[2][0]); acc[2][1] = fmaf(a.z, b.y, acc[2][1]);
        acc[2][2] = fmaf(a.z, b.z, acc[2][2]); acc[2][3] = fmaf(a.z, b.w, acc[2][3]);
        acc[3][0] = fmaf(a.w, b.x, acc[3][0]); acc[3][1] = fmaf(a.w, b.y, acc[3][1]);
        acc[3][2] = fmaf(a.w, b.z, acc[3][2]); acc[3][3] = fmaf(a.w, b.w, acc[3][3]);
    }
#pragma unroll
    for (int i = 0; i < 4; ++i) {
        int row = row0 + r0 + i;
        if (row < n) {
            float di = dinv[row];
            float4 o = make_float4(di * acc[i][0], di * acc[i][1], di * acc[i][2], di * acc[i][3]);
            *(float4*)(h1s + (size_t)row * C_HID + c0) = o;
        }
    }
}

// ------- fused layer-1 aggregate + bias + relu + GEMM2: h2s = dinv*(relu(agg)+b1)@W2 -------
// 512 threads = 8 waves = 8 nodes per block. W2 staged once per block.
__global__ void k_agg1g2(const int* __restrict__ row_start, const int* __restrict__ csr_src,
                         const float* __restrict__ h1s, const float* __restrict__ dinv,
                         const float* __restrict__ b1, const float* __restrict__ W2,
                         float* __restrict__ h2s, int n) {
    __shared__ float wl[C_HID * C_OUT];       // 10 KB
    __shared__ float rowbuf[8][C_HID];        // 2 KB, one row per wave
    const int t = threadIdx.x;
    for (int i = t; i < C_HID * C_OUT; i += 512) wl[i] = W2[i];
    // no barrier needed before use: each wave writes/reads only rowbuf[wid]; wl is
    // read after the whole block's staging -> need one barrier for wl.
    __syncthreads();

    const int wid  = t >> 6;
    const int lane = t & 63;
    const int node = blockIdx.x * 8 + wid;
    if (node >= n) return;

    int beg = row_start[node], end = row_start[node + 1];
    float a0 = h1s[(size_t)node * C_HID + lane];   // self term (prescaled by dinv[node])
    float a1 = 0.f, a2 = 0.f, a3 = 0.f;
    for (int j = beg; j < end; j += 64) {
        int sv = (j + lane < end) ? csr_src[j + lane] : 0;
        int m = min(64, end - j);
        int k = 0;
        for (; k + 4 <= m; k += 4) {
            int s0 = __shfl(sv, k),     s1 = __shfl(sv, k + 1);
            int s2 = __shfl(sv, k + 2), s3 = __shfl(sv, k + 3);
            a0 += h1s[(size_t)s0 * C_HID + lane];
            a1 += h1s[(size_t)s1 * C_HID + lane];
            a2 += h1s[(size_t)s2 * C_HID + lane];
            a3 += h1s[(size_t)s3 * C_HID + lane];
        }
        for (; k < m; ++k) {
            int s = __shfl(sv, k);
            a0 += h1s[(size_t)s * C_HID + lane];
        }
    }
    float accv = (a0 + a1) + (a2 + a3);
    float v = dinv[node] * accv + b1[lane];
    rowbuf[wid][lane] = v > 0.f ? v : 0.f;   // same-wave RAW: compiler inserts lgkmcnt

    // matvec: h2[c] = sum_k row[k] * W2[k][c], lanes c<40
    if (lane < C_OUT) {
        float acc2 = 0.f;
#pragma unroll 8
        for (int k = 0; k < C_HID; ++k)
            acc2 = fmaf(rowbuf[wid][k], wl[k * C_OUT + lane], acc2);
        h2s[(size_t)node * C_OUT + lane] = dinv[node] * acc2;
    }
}

// ---------------- layer-2 gather-aggregate + bias + log_softmax ----------------
__global__ void k_agg2(const int* __restrict__ row_start, const int* __restrict__ csr_src,
                       const float* __restrict__ h2s, const float* __restrict__ dinv,
                       const float* __restrict__ b2, float* __restrict__ out, int n) {
    int node = (blockIdx.x * 256 + threadIdx.x) >> 6;
    int lane = threadIdx.x & 63;
    if (node >= n) return;
    int beg = row_start[node], end = row_start[node + 1];
    float a0 = (lane < C_OUT) ? h2s[(size_t)node * C_OUT + lane] : 0.f;
    float a1 = 0.f, a2 = 0.f, a3 = 0.f;
    for (int j = beg; j < end; j += 64) {
        int sv = (j + lane < end) ? csr_src[j + lane] : 0;
        int m = min(64, end - j);
        int k = 0;
        for (; k + 4 <= m; k += 4) {
            int s0 = __shfl(sv, k),     s1 = __shfl(sv, k + 1);
            int s2 = __shfl(sv, k + 2), s3 = __shfl(sv, k + 3);
            if (lane < C_OUT) {
                a0 += h2s[(size_t)s0 * C_OUT + lane];
                a1 += h2s[(size_t)s1 * C_OUT + lane];
                a2 += h2s[(size_t)s2 * C_OUT + lane];
                a3 += h2s[(size_t)s3 * C_OUT + lane];
            }
        }
        for (; k < m; ++k) {
            int s = __shfl(sv, k);
            if (lane < C_OUT) a0 += h2s[(size_t)s * C_OUT + lane];
        }
    }
    float acc = (a0 + a1) + (a2 + a3);
    float v = (lane < C_OUT) ? dinv[node] * acc + b2[lane] : -INFINITY;
    float mx = v;
    for (int off = 32; off; off >>= 1) mx = fmaxf(mx, __shfl_xor(mx, off));
    float ex = (lane < C_OUT) ? expf(v - mx) : 0.f;
    float ss = ex;
    for (int off = 32; off; off >>= 1) ss += __shfl_xor(ss, off);
    float lse = mx + logf(ss);
    if (lane < C_OUT) out[(size_t)node * C_OUT + lane] = v - lse;
}

extern "C" void kernel_launch(void* const* d_in, const int* in_sizes, int n_in,
                              void* d_out, int out_size, void* d_ws, size_t ws_size,
                              hipStream_t stream) {
    const float* X   = (const float*)d_in[0];
    const int*   src = (const int*)d_in[1];
    const int*   dst = (const int*)d_in[2];
    const float* W1  = (const float*)d_in[3];
    const float* b1  = (const float*)d_in[4];
    const float* W2  = (const float*)d_in[5];
    const float* b2  = (const float*)d_in[6];
    float* out = (float*)d_out;

    const int N = in_sizes[0] / C_IN;
    const int E = in_sizes[1];
    const int NBKT = (N + BKT_N - 1) >> BKT_SH;
    const int nchunks = (E + CHUNK - 1) / CHUNK;   // must be <= 256

    // workspace layout
    char* ws = (char*)d_ws;
    size_t off = 0;
    auto take = [&](size_t bytes) { char* p = ws + off; off = (off + bytes + 255) & ~(size_t)255; return p; };
    int*   hist2d    = (int*)  take((size_t)nchunks * NBKT * 4);
    int*   base2d    = (int*)  take((size_t)nchunks * NBKT * 4);
    int*   tot       = (int*)  take(256 * 4);
    int*   bstart    = (int*)  take(257 * 4);
    unsigned int* bpack = (unsigned int*)take((size_t)E * 4);
    int*   csr_src   = (int*)  take((size_t)E * 4);
    int*   row_start = (int*)  take((size_t)(N + 1) * 4);
    float* dinv      = (float*)take((size_t)N * 4);
    float* h1s       = (float*)take((size_t)N * C_HID * 4);
    float* h2s       = (float*)take((size_t)N * C_OUT * 4);

    k_hist    <<<nchunks, 256, 0, stream>>>(dst, hist2d, E, NBKT);
    k_bktscan <<<NBKT, 256, 0, stream>>>(hist2d, base2d, tot, nchunks, NBKT);
    k_scan_bkt<<<1, 256, 0, stream>>>(tot, bstart, NBKT, E);
    k_binA    <<<nchunks, 256, 0, stream>>>(src, dst, bstart, base2d, bpack, E, NBKT);
    k_binB    <<<NBKT, 256, 0, stream>>>(bstart, bpack, row_start, dinv, csr_src, N, E, NBKT);

    k_gemm1   <<<(N + 63) / 64, 256, 0, stream>>>(X, W1, dinv, h1s, N);
    k_agg1g2  <<<(N + 7) / 8, 512, 0, stream>>>(row_start, csr_src, h1s, dinv, b1, W2, h2s, N);
    k_agg2    <<<((size_t)N * 64 + 255) / 256, 256, 0, stream>>>(row_start, csr_src, h2s, dinv, b2, out, N);
}

// Round 8
// 143.969 us; speedup vs baseline: 2.1407x; 1.0196x over previous
//
#include <hip/hip_runtime.h>
#include <math.h>

#define C_IN  128
#define C_HID 64
#define C_OUT 40
#define H2STR 64                      // padded bf16 row stride for h2 (128 B)

#define BKT_SH 9
#define BKT_N  (1 << BKT_SH)          // 512 nodes per bucket
#define CHUNK  4096                   // edges per hist/binA block
#define EPT    (CHUNK / 256)          // 16 edges per thread
// NOTE: nchunks (=196 for E=800k) must be <= 256 for k_bktscan's one-pass scan.

__device__ __forceinline__ float bf2f(unsigned short u) {
    return __uint_as_float(((unsigned int)u) << 16);
}
__device__ __forceinline__ unsigned short f2bf(float f) {   // round-to-nearest-even
    unsigned int x = __float_as_uint(f);
    return (unsigned short)((x + 0x7FFFu + ((x >> 16) & 1u)) >> 16);
}

// ---------------- pass 0: per-chunk, per-bucket histogram (no global atomics) ----------------
__global__ void k_hist(const int* __restrict__ dst, int* __restrict__ hist2d, int e, int nbkt) {
    __shared__ int hist[256];
    for (int i = threadIdx.x; i < nbkt; i += 256) hist[i] = 0;
    __syncthreads();
    int base = blockIdx.x * CHUNK;
#pragma unroll
    for (int j = 0; j < EPT; ++j) {
        int i = base + j * 256 + threadIdx.x;
        if (i < e) atomicAdd(&hist[dst[i] >> BKT_SH], 1);
    }
    __syncthreads();
    int* row = hist2d + (size_t)blockIdx.x * nbkt;
    for (int i = threadIdx.x; i < nbkt; i += 256) row[i] = hist[i];
}

// ---------------- per-bucket scan over chunks: base2d + tot ----------------
__global__ void k_bktscan(const int* __restrict__ hist2d, int* __restrict__ base2d,
                          int* __restrict__ tot, int nchunks, int nbkt) {
    __shared__ int wtot[4];
    const int b = blockIdx.x;
    const int t = threadIdx.x;
    int v = (t < nchunks) ? hist2d[(size_t)t * nbkt + b] : 0;
    int lane = t & 63, wv = t >> 6;
    int inc = v;
    for (int o = 1; o < 64; o <<= 1) { int u = __shfl_up(inc, o); if (lane >= o) inc += u; }
    if (lane == 63) wtot[wv] = inc;
    __syncthreads();
    int add = 0;
    for (int k = 0; k < wv; ++k) add += wtot[k];
    if (t < nchunks) base2d[(size_t)t * nbkt + b] = add + inc - v;   // exclusive within bucket
    if (t == 255) tot[b] = add + inc;                                // bucket total
}

// ---------------- tiny parallel scan over bucket totals -> bstart ----------------
__global__ void k_scan_bkt(const int* __restrict__ tot, int* __restrict__ bstart, int nbkt, int e) {
    __shared__ int wtot[4];
    const int t = threadIdx.x;
    int v = (t < nbkt) ? tot[t] : 0;
    int lane = t & 63, wv = t >> 6;
    int inc = v;
    for (int o = 1; o < 64; o <<= 1) { int u = __shfl_up(inc, o); if (lane >= o) inc += u; }
    if (lane == 63) wtot[wv] = inc;
    __syncthreads();
    int add = 0;
    for (int k = 0; k < wv; ++k) add += wtot[k];
    if (t < nbkt) bstart[t] = add + inc - v;
    if (t == 0) bstart[nbkt] = e;
}

// ---------------- pass A: LDS multisplit by bucket, coalesced flush (no global atomics) ----------------
__global__ void k_binA(const int* __restrict__ src, const int* __restrict__ dst,
                       const int* __restrict__ bstart, const int* __restrict__ base2d,
                       unsigned int* __restrict__ bpack, int e, int nbkt) {
    __shared__ int hist[256];          // histogram, then local cursors
    __shared__ int excl[256];
    __shared__ int gbase[256];
    __shared__ int wtot[4];
    __shared__ unsigned int stage[CHUNK];
    const int t = threadIdx.x;
    const int base = blockIdx.x * CHUNK;

    for (int i = t; i < nbkt; i += 256) hist[i] = 0;
    __syncthreads();

    unsigned int pk[EPT]; int bk[EPT];
#pragma unroll
    for (int j = 0; j < EPT; ++j) {
        int i = base + j * 256 + t;
        if (i < e) {
            int d = dst[i];
            pk[j] = (unsigned int)src[i] | ((unsigned int)d << 16);   // N < 65536
            bk[j] = d >> BKT_SH;
            atomicAdd(&hist[bk[j]], 1);
        } else bk[j] = -1;
    }
    __syncthreads();

    // parallel exclusive scan of hist[0..nbkt) (nbkt <= 256)
    {
        int lane = t & 63, wv = t >> 6;
        int v = (t < nbkt) ? hist[t] : 0;
        int inc = v;
        for (int o = 1; o < 64; o <<= 1) { int u = __shfl_up(inc, o); if (lane >= o) inc += u; }
        if (lane == 63) wtot[wv] = inc;
        __syncthreads();
        int add = 0;
        for (int k = 0; k < wv; ++k) add += wtot[k];
        if (t < nbkt) excl[t] = add + inc - v;
    }
    __syncthreads();

    // global base per bucket: precomputed, deterministic
    for (int i = t; i < nbkt; i += 256)
        gbase[i] = bstart[i] + base2d[(size_t)blockIdx.x * nbkt + i];
    __syncthreads();
    for (int i = t; i < nbkt; i += 256) hist[i] = 0;   // reuse as local cursors
    __syncthreads();

    // LDS scatter into bucket-sorted order
#pragma unroll
    for (int j = 0; j < EPT; ++j) {
        if (bk[j] >= 0) {
            int p = excl[bk[j]] + atomicAdd(&hist[bk[j]], 1);
            stage[p] = pk[j];
        }
    }
    __syncthreads();

    // coalesced flush: consecutive LDS slots in a bucket -> consecutive global
    int nchunk = min(CHUNK, e - base);
    for (int i = t; i < nchunk; i += 256) {
        unsigned int u = stage[i];
        int b = (int)(u >> 16) >> BKT_SH;
        bpack[gbase[b] + (i - excl[b])] = u;
    }
}

// ---------------- pass B: per-bucket counting sort -> deg/dinv/row_start/csr_src ----------------
__global__ void k_binB(const int* __restrict__ bstart, const unsigned int* __restrict__ bpack,
                       int* __restrict__ row_start, float* __restrict__ dinv,
                       int* __restrict__ csr_src, int n, int e, int nbkt) {
    __shared__ int hist[BKT_N];
    __shared__ int excl[BKT_N];
    __shared__ int wtot[4];
    const int t = threadIdx.x;
    const int b = blockIdx.x;
    const int beg = bstart[b], end = bstart[b + 1];
    const int nodebase = b << BKT_SH;
    const int nloc = min(BKT_N, n - nodebase);

    for (int i = t; i < nloc; i += 256) hist[i] = 0;
    __syncthreads();
    for (int i = beg + t; i < end; i += 256)
        atomicAdd(&hist[(int)(bpack[i] >> 16) - nodebase], 1);
    __syncthreads();

    // exclusive scan of hist[0..nloc) in 256-wide passes with carry
    int carry = 0;
    for (int base0 = 0; base0 < nloc; base0 += 256) {
        __syncthreads();
        int idx = base0 + t;
        int v = (idx < nloc) ? hist[idx] : 0;
        int inc = v; int lane = t & 63; int wv = t >> 6;
        for (int o = 1; o < 64; o <<= 1) { int u = __shfl_up(inc, o); if (lane >= o) inc += u; }
        if (lane == 63) wtot[wv] = inc;
        __syncthreads();
        int add = carry;
        for (int k = 0; k < wv; ++k) add += wtot[k];
        if (idx < nloc) excl[idx] = add + inc - v;
        carry += wtot[0] + wtot[1] + wtot[2] + wtot[3];
    }
    __syncthreads();

    // row_start + dinv (coalesced writes; deg == hist)
    for (int i = t; i < nloc; i += 256) {
        row_start[nodebase + i] = beg + excl[i];
        dinv[nodebase + i] = rsqrtf((float)hist[i] + 1.0f);   // +1 self loop
    }
    if (b == nbkt - 1 && t == 0) row_start[n] = e;
    __syncthreads();
    for (int i = t; i < nloc; i += 256) hist[i] = 0;   // reuse as cursors
    __syncthreads();

    // fine scatter within bucket window (single XCD L2 locality)
    for (int i = beg + t; i < end; i += 256) {
        unsigned int u = bpack[i];
        int dl = (int)(u >> 16) - nodebase;
        int p = beg + excl[dl] + atomicAdd(&hist[dl], 1);
        csr_src[p] = (int)(u & 0xFFFFu);
    }
}

// ---------------- GEMM1: h1b = bf16(dinv[row] * (X @ W1))  (N x 64) ----------------
__global__ void k_gemm1(const float* __restrict__ X, const float* __restrict__ W1,
                        const float* __restrict__ dinv, unsigned short* __restrict__ h1b, int n) {
    __shared__ float xt[C_IN][64];
    __shared__ float wl[C_IN * C_HID];
    const int t = threadIdx.x;
    const int row0 = blockIdx.x * 64;

    for (int i = t; i < C_IN * C_HID; i += 256) wl[i] = W1[i];
    {
        int r = t >> 2, q = t & 3;
        int grow = row0 + r;
        for (int j = 0; j < 8; ++j) {
            int k = q * 32 + j * 4;
            float4 v = make_float4(0.f, 0.f, 0.f, 0.f);
            if (grow < n) v = *(const float4*)(X + (size_t)grow * C_IN + k);
            xt[k + 0][r] = v.x; xt[k + 1][r] = v.y; xt[k + 2][r] = v.z; xt[k + 3][r] = v.w;
        }
    }
    __syncthreads();

    const int rg = t >> 4, cg = t & 15;
    const int r0 = rg * 4, c0 = cg * 4;
    float acc[4][4] = {};
#pragma unroll 4
    for (int k = 0; k < C_IN; ++k) {
        float4 a = *(const float4*)&xt[k][r0];
        float4 b = *(const float4*)&wl[k * C_HID + c0];
        acc[0][0] = fmaf(a.x, b.x, acc[0][0]); acc[0][1] = fmaf(a.x, b.y, acc[0][1]);
        acc[0][2] = fmaf(a.x, b.z, acc[0][2]); acc[0][3] = fmaf(a.x, b.w, acc[0][3]);
        acc[1][0] = fmaf(a.y, b.x, acc[1][0]); acc[1][1] = fmaf(a.y, b.y, acc[1][1]);
        acc[1][2] = fmaf(a.y, b.z, acc[1][2]); acc[1][3] = fmaf(a.y, b.w, acc[1][3]);
        acc[2][0] = fmaf(a.z, b.x, acc[2][0]); acc[2][1] = fmaf(a.z, b.y, acc[2][1]);
        acc[2][2] = fmaf(a.z, b.z, acc[2][2]); acc[2][3] = fmaf(a.z, b.w, acc[2][3]);
        acc[3][0] = fmaf(a.w, b.x, acc[3][0]); acc[3][1] = fmaf(a.w, b.y, acc[3][1]);
        acc[3][2] = fmaf(a.w, b.z, acc[3][2]); acc[3][3] = fmaf(a.w, b.w, acc[3][3]);
    }
#pragma unroll
    for (int i = 0; i < 4; ++i) {
        int row = row0 + r0 + i;
        if (row < n) {
            float di = dinv[row];
            ushort4 o;
            o.x = f2bf(di * acc[i][0]); o.y = f2bf(di * acc[i][1]);
            o.z = f2bf(di * acc[i][2]); o.w = f2bf(di * acc[i][3]);
            *(ushort4*)(h1b + (size_t)row * C_HID + c0) = o;
        }
    }
}

// ------- fused layer-1 aggregate + bias + relu + GEMM2 (bf16 in, bf16 out) -------
// 512 threads = 8 waves = 8 nodes per block. W2 staged once per block.
__global__ void k_agg1g2(const int* __restrict__ row_start, const int* __restrict__ csr_src,
                         const unsigned short* __restrict__ h1b, const float* __restrict__ dinv,
                         const float* __restrict__ b1, const float* __restrict__ W2,
                         unsigned short* __restrict__ h2b, int n) {
    __shared__ float wl[C_HID * C_OUT];       // 10 KB
    __shared__ float rowbuf[8][C_HID];        // 2 KB, one row per wave
    const int t = threadIdx.x;
    for (int i = t; i < C_HID * C_OUT; i += 512) wl[i] = W2[i];
    __syncthreads();

    const int wid  = t >> 6;
    const int lane = t & 63;
    const int node = blockIdx.x * 8 + wid;
    if (node >= n) return;

    int beg = row_start[node], end = row_start[node + 1];
    float a0 = bf2f(h1b[(size_t)node * C_HID + lane]);   // self term (prescaled)
    float a1 = 0.f, a2 = 0.f, a3 = 0.f, a4 = 0.f, a5 = 0.f, a6 = 0.f, a7 = 0.f;
    for (int j = beg; j < end; j += 64) {
        int sv = (j + lane < end) ? csr_src[j + lane] : 0;
        int m = min(64, end - j);
        int k = 0;
        for (; k + 8 <= m; k += 8) {
            int s0 = __shfl(sv, k),     s1 = __shfl(sv, k + 1);
            int s2 = __shfl(sv, k + 2), s3 = __shfl(sv, k + 3);
            int s4 = __shfl(sv, k + 4), s5 = __shfl(sv, k + 5);
            int s6 = __shfl(sv, k + 6), s7 = __shfl(sv, k + 7);
            a0 += bf2f(h1b[(size_t)s0 * C_HID + lane]);
            a1 += bf2f(h1b[(size_t)s1 * C_HID + lane]);
            a2 += bf2f(h1b[(size_t)s2 * C_HID + lane]);
            a3 += bf2f(h1b[(size_t)s3 * C_HID + lane]);
            a4 += bf2f(h1b[(size_t)s4 * C_HID + lane]);
            a5 += bf2f(h1b[(size_t)s5 * C_HID + lane]);
            a6 += bf2f(h1b[(size_t)s6 * C_HID + lane]);
            a7 += bf2f(h1b[(size_t)s7 * C_HID + lane]);
        }
        for (; k < m; ++k) {
            int s = __shfl(sv, k);
            a0 += bf2f(h1b[(size_t)s * C_HID + lane]);
        }
    }
    float accv = ((a0 + a1) + (a2 + a3)) + ((a4 + a5) + (a6 + a7));
    float v = dinv[node] * accv + b1[lane];
    rowbuf[wid][lane] = v > 0.f ? v : 0.f;

    // matvec: h2[c] = sum_k row[k] * W2[k][c], lanes c<40
    if (lane < C_OUT) {
        float acc2 = 0.f;
#pragma unroll 8
        for (int k = 0; k < C_HID; ++k)
            acc2 = fmaf(rowbuf[wid][k], wl[k * C_OUT + lane], acc2);
        h2b[(size_t)node * H2STR + lane] = f2bf(dinv[node] * acc2);
    }
}

// ---------------- layer-2 gather-aggregate + bias + log_softmax (bf16 in) ----------------
__global__ void k_agg2(const int* __restrict__ row_start, const int* __restrict__ csr_src,
                       const unsigned short* __restrict__ h2b, const float* __restrict__ dinv,
                       const float* __restrict__ b2, float* __restrict__ out, int n) {
    int node = (blockIdx.x * 256 + threadIdx.x) >> 6;
    int lane = threadIdx.x & 63;
    if (node >= n) return;
    int beg = row_start[node], end = row_start[node + 1];
    float a0 = (lane < C_OUT) ? bf2f(h2b[(size_t)node * H2STR + lane]) : 0.f;
    float a1 = 0.f, a2 = 0.f, a3 = 0.f, a4 = 0.f, a5 = 0.f, a6 = 0.f, a7 = 0.f;
    for (int j = beg; j < end; j += 64) {
        int sv = (j + lane < end) ? csr_src[j + lane] : 0;
        int m = min(64, end - j);
        int k = 0;
        for (; k + 8 <= m; k += 8) {
            int s0 = __shfl(sv, k),     s1 = __shfl(sv, k + 1);
            int s2 = __shfl(sv, k + 2), s3 = __shfl(sv, k + 3);
            int s4 = __shfl(sv, k + 4), s5 = __shfl(sv, k + 5);
            int s6 = __shfl(sv, k + 6), s7 = __shfl(sv, k + 7);
            if (lane < C_OUT) {
                a0 += bf2f(h2b[(size_t)s0 * H2STR + lane]);
                a1 += bf2f(h2b[(size_t)s1 * H2STR + lane]);
                a2 += bf2f(h2b[(size_t)s2 * H2STR + lane]);
                a3 += bf2f(h2b[(size_t)s3 * H2STR + lane]);
                a4 += bf2f(h2b[(size_t)s4 * H2STR + lane]);
                a5 += bf2f(h2b[(size_t)s5 * H2STR + lane]);
                a6 += bf2f(h2b[(size_t)s6 * H2STR + lane]);
                a7 += bf2f(h2b[(size_t)s7 * H2STR + lane]);
            }
        }
        for (; k < m; ++k) {
            int s = __shfl(sv, k);
            if (lane < C_OUT) a0 += bf2f(h2b[(size_t)s * H2STR + lane]);
        }
    }
    float acc = ((a0 + a1) + (a2 + a3)) + ((a4 + a5) + (a6 + a7));
    float v = (lane < C_OUT) ? dinv[node] * acc + b2[lane] : -INFINITY;
    float mx = v;
    for (int off = 32; off; off >>= 1) mx = fmaxf(mx, __shfl_xor(mx, off));
    float ex = (lane < C_OUT) ? expf(v - mx) : 0.f;
    float ss = ex;
    for (int off = 32; off; off >>= 1) ss += __shfl_xor(ss, off);
    float lse = mx + logf(ss);
    if (lane < C_OUT) out[(size_t)node * C_OUT + lane] = v - lse;
}

extern "C" void kernel_launch(void* const* d_in, const int* in_sizes, int n_in,
                              void* d_out, int out_size, void* d_ws, size_t ws_size,
                              hipStream_t stream) {
    const float* X   = (const float*)d_in[0];
    const int*   src = (const int*)d_in[1];
    const int*   dst = (const int*)d_in[2];
    const float* W1  = (const float*)d_in[3];
    const float* b1  = (const float*)d_in[4];
    const float* W2  = (const float*)d_in[5];
    const float* b2  = (const float*)d_in[6];
    float* out = (float*)d_out;

    const int N = in_sizes[0] / C_IN;
    const int E = in_sizes[1];
    const int NBKT = (N + BKT_N - 1) >> BKT_SH;
    const int nchunks = (E + CHUNK - 1) / CHUNK;   // must be <= 256

    // workspace layout
    char* ws = (char*)d_ws;
    size_t off = 0;
    auto take = [&](size_t bytes) { char* p = ws + off; off = (off + bytes + 255) & ~(size_t)255; return p; };
    int*   hist2d    = (int*)  take((size_t)nchunks * NBKT * 4);
    int*   base2d    = (int*)  take((size_t)nchunks * NBKT * 4);
    int*   tot       = (int*)  take(256 * 4);
    int*   bstart    = (int*)  take(257 * 4);
    unsigned int* bpack = (unsigned int*)take((size_t)E * 4);
    int*   csr_src   = (int*)  take((size_t)E * 4);
    int*   row_start = (int*)  take((size_t)(N + 1) * 4);
    float* dinv      = (float*)take((size_t)N * 4);
    unsigned short* h1b = (unsigned short*)take((size_t)N * C_HID * 2);
    unsigned short* h2b = (unsigned short*)take((size_t)N * H2STR * 2);

    k_hist    <<<nchunks, 256, 0, stream>>>(dst, hist2d, E, NBKT);
    k_bktscan <<<NBKT, 256, 0, stream>>>(hist2d, base2d, tot, nchunks, NBKT);
    k_scan_bkt<<<1, 256, 0, stream>>>(tot, bstart, NBKT, E);
    k_binA    <<<nchunks, 256, 0, stream>>>(src, dst, bstart, base2d, bpack, E, NBKT);
    k_binB    <<<NBKT, 256, 0, stream>>>(bstart, bpack, row_start, dinv, csr_src, N, E, NBKT);

    k_gemm1   <<<(N + 63) / 64, 256, 0, stream>>>(X, W1, dinv, h1b, N);
    k_agg1g2  <<<(N + 7) / 8, 512, 0, stream>>>(row_start, csr_src, h1b, dinv, b1, W2, h2b, N);
    k_agg2    <<<((size_t)N * 64 + 255) / 256, 256, 0, stream>>>(row_start, csr_src, h2b, dinv, b2, out, N);
}

// Round 9
// 143.927 us; speedup vs baseline: 2.1413x; 1.0003x over previous
//
#include <hip/hip_runtime.h>
#include <math.h>

#define C_IN  128
#define C_HID 64
#define C_OUT 40
#define H2STR 64                      // padded bf16 row stride for h2 (128 B)

#define BKT_SH 9
#define BKT_N  (1 << BKT_SH)          // 512 nodes per bucket
#define CHUNK  4096                   // edges per hist/binA block
#define EPT    (CHUNK / 256)          // 16 edges per thread
// NOTE: nchunks (=196 for E=800k) must be <= 256 for k_bktscan's one-pass scan.

__device__ __forceinline__ float bf2f(unsigned short u) {
    return __uint_as_float(((unsigned int)u) << 16);
}
__device__ __forceinline__ unsigned short f2bf(float f) {   // round-to-nearest-even
    unsigned int x = __float_as_uint(f);
    return (unsigned short)((x + 0x7FFFu + ((x >> 16) & 1u)) >> 16);
}

// ---------------- pass 0: per-chunk, per-bucket histogram (no global atomics) ----------------
__global__ void k_hist(const int* __restrict__ dst, int* __restrict__ hist2d, int e, int nbkt) {
    __shared__ int hist[256];
    for (int i = threadIdx.x; i < nbkt; i += 256) hist[i] = 0;
    __syncthreads();
    int base = blockIdx.x * CHUNK;
#pragma unroll
    for (int j = 0; j < EPT; ++j) {
        int i = base + j * 256 + threadIdx.x;
        if (i < e) atomicAdd(&hist[dst[i] >> BKT_SH], 1);
    }
    __syncthreads();
    int* row = hist2d + (size_t)blockIdx.x * nbkt;
    for (int i = threadIdx.x; i < nbkt; i += 256) row[i] = hist[i];
}

// ---------------- per-bucket scan over chunks: base2d + tot ----------------
__global__ void k_bktscan(const int* __restrict__ hist2d, int* __restrict__ base2d,
                          int* __restrict__ tot, int nchunks, int nbkt) {
    __shared__ int wtot[4];
    const int b = blockIdx.x;
    const int t = threadIdx.x;
    int v = (t < nchunks) ? hist2d[(size_t)t * nbkt + b] : 0;
    int lane = t & 63, wv = t >> 6;
    int inc = v;
    for (int o = 1; o < 64; o <<= 1) { int u = __shfl_up(inc, o); if (lane >= o) inc += u; }
    if (lane == 63) wtot[wv] = inc;
    __syncthreads();
    int add = 0;
    for (int k = 0; k < wv; ++k) add += wtot[k];
    if (t < nchunks) base2d[(size_t)t * nbkt + b] = add + inc - v;   // exclusive within bucket
    if (t == 255) tot[b] = add + inc;                                // bucket total
}

// ---------------- tiny parallel scan over bucket totals -> bstart ----------------
__global__ void k_scan_bkt(const int* __restrict__ tot, int* __restrict__ bstart, int nbkt, int e) {
    __shared__ int wtot[4];
    const int t = threadIdx.x;
    int v = (t < nbkt) ? tot[t] : 0;
    int lane = t & 63, wv = t >> 6;
    int inc = v;
    for (int o = 1; o < 64; o <<= 1) { int u = __shfl_up(inc, o); if (lane >= o) inc += u; }
    if (lane == 63) wtot[wv] = inc;
    __syncthreads();
    int add = 0;
    for (int k = 0; k < wv; ++k) add += wtot[k];
    if (t < nbkt) bstart[t] = add + inc - v;
    if (t == 0) bstart[nbkt] = e;
}

// ---------------- pass A: LDS multisplit by bucket, coalesced flush (no global atomics) ----------------
__global__ void k_binA(const int* __restrict__ src, const int* __restrict__ dst,
                       const int* __restrict__ bstart, const int* __restrict__ base2d,
                       unsigned int* __restrict__ bpack, int e, int nbkt) {
    __shared__ int hist[256];          // histogram, then local cursors
    __shared__ int excl[256];
    __shared__ int gbase[256];
    __shared__ int wtot[4];
    __shared__ unsigned int stage[CHUNK];
    const int t = threadIdx.x;
    const int base = blockIdx.x * CHUNK;

    for (int i = t; i < nbkt; i += 256) hist[i] = 0;
    __syncthreads();

    unsigned int pk[EPT]; int bk[EPT];
#pragma unroll
    for (int j = 0; j < EPT; ++j) {
        int i = base + j * 256 + t;
        if (i < e) {
            int d = dst[i];
            pk[j] = (unsigned int)src[i] | ((unsigned int)d << 16);   // N < 65536
            bk[j] = d >> BKT_SH;
            atomicAdd(&hist[bk[j]], 1);
        } else bk[j] = -1;
    }
    __syncthreads();

    // parallel exclusive scan of hist[0..nbkt) (nbkt <= 256)
    {
        int lane = t & 63, wv = t >> 6;
        int v = (t < nbkt) ? hist[t] : 0;
        int inc = v;
        for (int o = 1; o < 64; o <<= 1) { int u = __shfl_up(inc, o); if (lane >= o) inc += u; }
        if (lane == 63) wtot[wv] = inc;
        __syncthreads();
        int add = 0;
        for (int k = 0; k < wv; ++k) add += wtot[k];
        if (t < nbkt) excl[t] = add + inc - v;
    }
    __syncthreads();

    // global base per bucket: precomputed, deterministic
    for (int i = t; i < nbkt; i += 256)
        gbase[i] = bstart[i] + base2d[(size_t)blockIdx.x * nbkt + i];
    __syncthreads();
    for (int i = t; i < nbkt; i += 256) hist[i] = 0;   // reuse as local cursors
    __syncthreads();

    // LDS scatter into bucket-sorted order
#pragma unroll
    for (int j = 0; j < EPT; ++j) {
        if (bk[j] >= 0) {
            int p = excl[bk[j]] + atomicAdd(&hist[bk[j]], 1);
            stage[p] = pk[j];
        }
    }
    __syncthreads();

    // coalesced flush: consecutive LDS slots in a bucket -> consecutive global
    int nchunk = min(CHUNK, e - base);
    for (int i = t; i < nchunk; i += 256) {
        unsigned int u = stage[i];
        int b = (int)(u >> 16) >> BKT_SH;
        bpack[gbase[b] + (i - excl[b])] = u;
    }
}

// ---------------- pass B: per-bucket counting sort -> deg/dinv/row_start/csr_src ----------------
__global__ void k_binB(const int* __restrict__ bstart, const unsigned int* __restrict__ bpack,
                       int* __restrict__ row_start, float* __restrict__ dinv,
                       int* __restrict__ csr_src, int n, int e, int nbkt) {
    __shared__ int hist[BKT_N];
    __shared__ int excl[BKT_N];
    __shared__ int wtot[4];
    const int t = threadIdx.x;
    const int b = blockIdx.x;
    const int beg = bstart[b], end = bstart[b + 1];
    const int nodebase = b << BKT_SH;
    const int nloc = min(BKT_N, n - nodebase);

    for (int i = t; i < nloc; i += 256) hist[i] = 0;
    __syncthreads();
    for (int i = beg + t; i < end; i += 256)
        atomicAdd(&hist[(int)(bpack[i] >> 16) - nodebase], 1);
    __syncthreads();

    // exclusive scan of hist[0..nloc) in 256-wide passes with carry
    int carry = 0;
    for (int base0 = 0; base0 < nloc; base0 += 256) {
        __syncthreads();
        int idx = base0 + t;
        int v = (idx < nloc) ? hist[idx] : 0;
        int inc = v; int lane = t & 63; int wv = t >> 6;
        for (int o = 1; o < 64; o <<= 1) { int u = __shfl_up(inc, o); if (lane >= o) inc += u; }
        if (lane == 63) wtot[wv] = inc;
        __syncthreads();
        int add = carry;
        for (int k = 0; k < wv; ++k) add += wtot[k];
        if (idx < nloc) excl[idx] = add + inc - v;
        carry += wtot[0] + wtot[1] + wtot[2] + wtot[3];
    }
    __syncthreads();

    // row_start + dinv (coalesced writes; deg == hist)
    for (int i = t; i < nloc; i += 256) {
        row_start[nodebase + i] = beg + excl[i];
        dinv[nodebase + i] = rsqrtf((float)hist[i] + 1.0f);   // +1 self loop
    }
    if (b == nbkt - 1 && t == 0) row_start[n] = e;
    __syncthreads();
    for (int i = t; i < nloc; i += 256) hist[i] = 0;   // reuse as cursors
    __syncthreads();

    // fine scatter within bucket window (single XCD L2 locality)
    for (int i = beg + t; i < end; i += 256) {
        unsigned int u = bpack[i];
        int dl = (int)(u >> 16) - nodebase;
        int p = beg + excl[dl] + atomicAdd(&hist[dl], 1);
        csr_src[p] = (int)(u & 0xFFFFu);
    }
}

// ---------------- GEMM1: h1b = bf16(dinv[row] * (X @ W1))  (N x 64) ----------------
__global__ void k_gemm1(const float* __restrict__ X, const float* __restrict__ W1,
                        const float* __restrict__ dinv, unsigned short* __restrict__ h1b, int n) {
    __shared__ float xt[C_IN][64];
    __shared__ float wl[C_IN * C_HID];
    const int t = threadIdx.x;
    const int row0 = blockIdx.x * 64;

    for (int i = t; i < C_IN * C_HID; i += 256) wl[i] = W1[i];
    {
        int r = t >> 2, q = t & 3;
        int grow = row0 + r;
        for (int j = 0; j < 8; ++j) {
            int k = q * 32 + j * 4;
            float4 v = make_float4(0.f, 0.f, 0.f, 0.f);
            if (grow < n) v = *(const float4*)(X + (size_t)grow * C_IN + k);
            xt[k + 0][r] = v.x; xt[k + 1][r] = v.y; xt[k + 2][r] = v.z; xt[k + 3][r] = v.w;
        }
    }
    __syncthreads();

    const int rg = t >> 4, cg = t & 15;
    const int r0 = rg * 4, c0 = cg * 4;
    float acc[4][4] = {};
#pragma unroll 4
    for (int k = 0; k < C_IN; ++k) {
        float4 a = *(const float4*)&xt[k][r0];
        float4 b = *(const float4*)&wl[k * C_HID + c0];
        acc[0][0] = fmaf(a.x, b.x, acc[0][0]); acc[0][1] = fmaf(a.x, b.y, acc[0][1]);
        acc[0][2] = fmaf(a.x, b.z, acc[0][2]); acc[0][3] = fmaf(a.x, b.w, acc[0][3]);
        acc[1][0] = fmaf(a.y, b.x, acc[1][0]); acc[1][1] = fmaf(a.y, b.y, acc[1][1]);
        acc[1][2] = fmaf(a.y, b.z, acc[1][2]); acc[1][3] = fmaf(a.y, b.w, acc[1][3]);
        acc[2][0] = fmaf(a.z, b.x, acc[2][0]); acc[2][1] = fmaf(a.z, b.y, acc[2][1]);
        acc[2][2] = fmaf(a.z, b.z, acc[2][2]); acc[2][3] = fmaf(a.z, b.w, acc[2][3]);
        acc[3][0] = fmaf(a.w, b.x, acc[3][0]); acc[3][1] = fmaf(a.w, b.y, acc[3][1]);
        acc[3][2] = fmaf(a.w, b.z, acc[3][2]); acc[3][3] = fmaf(a.w, b.w, acc[3][3]);
    }
#pragma unroll
    for (int i = 0; i < 4; ++i) {
        int row = row0 + r0 + i;
        if (row < n) {
            float di = dinv[row];
            ushort4 o;
            o.x = f2bf(di * acc[i][0]); o.y = f2bf(di * acc[i][1]);
            o.z = f2bf(di * acc[i][2]); o.w = f2bf(di * acc[i][3]);
            *(ushort4*)(h1b + (size_t)row * C_HID + c0) = o;
        }
    }
}

// ------- fused layer-1 aggregate + bias + relu + GEMM2 (bf16 in, bf16 out) -------
// 512 threads = 8 waves = 8 nodes per block. W2 staged once per block.
// Gather: 16 independent predicated chains -> 16 loads in flight, no serial tail.
__global__ void k_agg1g2(const int* __restrict__ row_start, const int* __restrict__ csr_src,
                         const unsigned short* __restrict__ h1b, const float* __restrict__ dinv,
                         const float* __restrict__ b1, const float* __restrict__ W2,
                         unsigned short* __restrict__ h2b, int n) {
    __shared__ float wl[C_HID * C_OUT];       // 10 KB
    __shared__ float rowbuf[8][C_HID];        // 2 KB, one row per wave
    const int t = threadIdx.x;
    for (int i = t; i < C_HID * C_OUT; i += 512) wl[i] = W2[i];
    __syncthreads();

    const int wid  = t >> 6;
    const int lane = t & 63;
    const int node = blockIdx.x * 8 + wid;
    if (node >= n) return;

    int beg = row_start[node], end = row_start[node + 1];
    float acc[16];
#pragma unroll
    for (int i = 0; i < 16; ++i) acc[i] = 0.f;
    acc[0] = bf2f(h1b[(size_t)node * C_HID + lane]);   // self term (prescaled)

    for (int j = beg; j < end; j += 64) {
        int sv = (j + lane < end) ? csr_src[j + lane] : 0;   // OOB lanes -> node 0 (hot line)
        int m = min(64, end - j);
        for (int k = 0; k < m; k += 16) {
#pragma unroll
            for (int i = 0; i < 16; ++i) {
                int   s = __shfl(sv, k + i);                 // k+i <= 63 always
                float f = (k + i < m) ? 1.f : 0.f;           // mask tail via multiply
                acc[i] = fmaf(f, bf2f(h1b[(size_t)s * C_HID + lane]), acc[i]);
            }
        }
    }
    float accv = (((acc[0] + acc[1]) + (acc[2] + acc[3])) + ((acc[4] + acc[5]) + (acc[6] + acc[7])))
               + (((acc[8] + acc[9]) + (acc[10] + acc[11])) + ((acc[12] + acc[13]) + (acc[14] + acc[15])));
    float v = dinv[node] * accv + b1[lane];
    rowbuf[wid][lane] = v > 0.f ? v : 0.f;

    // matvec: h2[c] = sum_k row[k] * W2[k][c], lanes c<40
    if (lane < C_OUT) {
        float acc2 = 0.f;
#pragma unroll 8
        for (int k = 0; k < C_HID; ++k)
            acc2 = fmaf(rowbuf[wid][k], wl[k * C_OUT + lane], acc2);
        h2b[(size_t)node * H2STR + lane] = f2bf(dinv[node] * acc2);
    }
}

// ---------------- layer-2 gather-aggregate + bias + log_softmax (bf16 in) ----------------
__global__ void k_agg2(const int* __restrict__ row_start, const int* __restrict__ csr_src,
                       const unsigned short* __restrict__ h2b, const float* __restrict__ dinv,
                       const float* __restrict__ b2, float* __restrict__ out, int n) {
    int node = (blockIdx.x * 256 + threadIdx.x) >> 6;
    int lane = threadIdx.x & 63;
    if (node >= n) return;
    int beg = row_start[node], end = row_start[node + 1];
    float acc[16];
#pragma unroll
    for (int i = 0; i < 16; ++i) acc[i] = 0.f;
    acc[0] = (lane < C_OUT) ? bf2f(h2b[(size_t)node * H2STR + lane]) : 0.f;

    for (int j = beg; j < end; j += 64) {
        int sv = (j + lane < end) ? csr_src[j + lane] : 0;
        int m = min(64, end - j);
        for (int k = 0; k < m; k += 16) {
#pragma unroll
            for (int i = 0; i < 16; ++i) {
                int   s = __shfl(sv, k + i);
                float f = (k + i < m) ? 1.f : 0.f;
                acc[i] = fmaf(f, bf2f(h2b[(size_t)s * H2STR + lane]), acc[i]);
            }
        }
    }
    float accv = (((acc[0] + acc[1]) + (acc[2] + acc[3])) + ((acc[4] + acc[5]) + (acc[6] + acc[7])))
               + (((acc[8] + acc[9]) + (acc[10] + acc[11])) + ((acc[12] + acc[13]) + (acc[14] + acc[15])));
    float v = (lane < C_OUT) ? dinv[node] * accv + b2[lane] : -INFINITY;
    float mx = v;
    for (int off = 32; off; off >>= 1) mx = fmaxf(mx, __shfl_xor(mx, off));
    float ex = (lane < C_OUT) ? expf(v - mx) : 0.f;
    float ss = ex;
    for (int off = 32; off; off >>= 1) ss += __shfl_xor(ss, off);
    float lse = mx + logf(ss);
    if (lane < C_OUT) out[(size_t)node * C_OUT + lane] = v - lse;
}

extern "C" void kernel_launch(void* const* d_in, const int* in_sizes, int n_in,
                              void* d_out, int out_size, void* d_ws, size_t ws_size,
                              hipStream_t stream) {
    const float* X   = (const float*)d_in[0];
    const int*   src = (const int*)d_in[1];
    const int*   dst = (const int*)d_in[2];
    const float* W1  = (const float*)d_in[3];
    const float* b1  = (const float*)d_in[4];
    const float* W2  = (const float*)d_in[5];
    const float* b2  = (const float*)d_in[6];
    float* out = (float*)d_out;

    const int N = in_sizes[0] / C_IN;
    const int E = in_sizes[1];
    const int NBKT = (N + BKT_N - 1) >> BKT_SH;
    const int nchunks = (E + CHUNK - 1) / CHUNK;   // must be <= 256

    // workspace layout
    char* ws = (char*)d_ws;
    size_t off = 0;
    auto take = [&](size_t bytes) { char* p = ws + off; off = (off + bytes + 255) & ~(size_t)255; return p; };
    int*   hist2d    = (int*)  take((size_t)nchunks * NBKT * 4);
    int*   base2d    = (int*)  take((size_t)nchunks * NBKT * 4);
    int*   tot       = (int*)  take(256 * 4);
    int*   bstart    = (int*)  take(257 * 4);
    unsigned int* bpack = (unsigned int*)take((size_t)E * 4);
    int*   csr_src   = (int*)  take((size_t)E * 4);
    int*   row_start = (int*)  take((size_t)(N + 1) * 4);
    float* dinv      = (float*)take((size_t)N * 4);
    unsigned short* h1b = (unsigned short*)take((size_t)N * C_HID * 2);
    unsigned short* h2b = (unsigned short*)take((size_t)N * H2STR * 2);

    k_hist    <<<nchunks, 256, 0, stream>>>(dst, hist2d, E, NBKT);
    k_bktscan <<<NBKT, 256, 0, stream>>>(hist2d, base2d, tot, nchunks, NBKT);
    k_scan_bkt<<<1, 256, 0, stream>>>(tot, bstart, NBKT, E);
    k_binA    <<<nchunks, 256, 0, stream>>>(src, dst, bstart, base2d, bpack, E, NBKT);
    k_binB    <<<NBKT, 256, 0, stream>>>(bstart, bpack, row_start, dinv, csr_src, N, E, NBKT);

    k_gemm1   <<<(N + 63) / 64, 256, 0, stream>>>(X, W1, dinv, h1b, N);
    k_agg1g2  <<<(N + 7) / 8, 512, 0, stream>>>(row_start, csr_src, h1b, dinv, b1, W2, h2b, N);
    k_agg2    <<<((size_t)N * 64 + 255) / 256, 256, 0, stream>>>(row_start, csr_src, h2b, dinv, b2, out, N);
}

// Round 10
// 121.891 us; speedup vs baseline: 2.5284x; 1.1808x over previous
//
#include <hip/hip_runtime.h>
#include <math.h>

#define C_IN  128
#define C_HID 64
#define C_OUT 40
#define H1DW  32                      // dwords per h1 row (64 bf16)
#define H2DW  20                      // dwords per h2 row (40 bf16)

#define BKT_SH 7
#define BKT_N  (1 << BKT_SH)          // 128 nodes per bucket
#define CHUNK  1024                   // edges per hist/binA block
#define EPT    (CHUNK / 256)          // 4 edges per thread

__device__ __forceinline__ float bf2f(unsigned short u) {
    return __uint_as_float(((unsigned int)u) << 16);
}
__device__ __forceinline__ unsigned short f2bf(float f) {   // round-to-nearest-even
    unsigned int x = __float_as_uint(f);
    return (unsigned short)((x + 0x7FFFu + ((x >> 16) & 1u)) >> 16);
}

// ---------------- pass 0: per-chunk, per-bucket histogram (no global atomics) ----------------
__global__ void k_hist(const int* __restrict__ dst, int* __restrict__ hist2d, int e, int nbkt) {
    __shared__ int hist[512];
    for (int i = threadIdx.x; i < nbkt; i += 256) hist[i] = 0;
    __syncthreads();
    int base = blockIdx.x * CHUNK;
#pragma unroll
    for (int j = 0; j < EPT; ++j) {
        int i = base + j * 256 + threadIdx.x;
        if (i < e) atomicAdd(&hist[dst[i] >> BKT_SH], 1);
    }
    __syncthreads();
    int* row = hist2d + (size_t)blockIdx.x * nbkt;
    for (int i = threadIdx.x; i < nbkt; i += 256) row[i] = hist[i];
}

// ---------------- per-bucket scan over chunks (looped, carry): base2d + tot ----------------
__global__ void k_bktscan(const int* __restrict__ hist2d, int* __restrict__ base2d,
                          int* __restrict__ tot, int nchunks, int nbkt) {
    __shared__ int wtot[4];
    const int b = blockIdx.x;
    const int t = threadIdx.x;
    const int lane = t & 63, wv = t >> 6;
    int carry = 0;
    for (int c0 = 0; c0 < nchunks; c0 += 256) {
        int c = c0 + t;
        int v = (c < nchunks) ? hist2d[(size_t)c * nbkt + b] : 0;
        int inc = v;
        for (int o = 1; o < 64; o <<= 1) { int u = __shfl_up(inc, o); if (lane >= o) inc += u; }
        if (lane == 63) wtot[wv] = inc;
        __syncthreads();
        int add = carry;
        for (int k = 0; k < wv; ++k) add += wtot[k];
        if (c < nchunks) base2d[(size_t)c * nbkt + b] = add + inc - v;
        carry += wtot[0] + wtot[1] + wtot[2] + wtot[3];
        __syncthreads();
    }
    if (t == 0) tot[b] = carry;
}

// ---------------- scan over bucket totals (looped, carry) -> bstart ----------------
__global__ void k_scan_bkt(const int* __restrict__ tot, int* __restrict__ bstart, int nbkt, int e) {
    __shared__ int wtot[4];
    const int t = threadIdx.x;
    const int lane = t & 63, wv = t >> 6;
    int carry = 0;
    for (int b0 = 0; b0 < nbkt; b0 += 256) {
        int b = b0 + t;
        int v = (b < nbkt) ? tot[b] : 0;
        int inc = v;
        for (int o = 1; o < 64; o <<= 1) { int u = __shfl_up(inc, o); if (lane >= o) inc += u; }
        if (lane == 63) wtot[wv] = inc;
        __syncthreads();
        int add = carry;
        for (int k = 0; k < wv; ++k) add += wtot[k];
        if (b < nbkt) bstart[b] = add + inc - v;
        carry += wtot[0] + wtot[1] + wtot[2] + wtot[3];
        __syncthreads();
    }
    if (t == 0) bstart[nbkt] = e;
}

// ---------------- pass A: LDS multisplit by bucket (hist reused from hist2d) ----------------
__global__ void k_binA(const int* __restrict__ src, const int* __restrict__ dst,
                       const int* __restrict__ bstart, const int* __restrict__ hist2d,
                       const int* __restrict__ base2d, unsigned int* __restrict__ bpack,
                       int e, int nbkt) {
    __shared__ int hist[512];          // local cursors
    __shared__ int excl[512];
    __shared__ int gbase[512];
    __shared__ int wtot[4];
    __shared__ unsigned int stage[CHUNK];
    const int t = threadIdx.x;
    const int base = blockIdx.x * CHUNK;
    const int lane = t & 63, wv = t >> 6;

    // chunk-local exclusive scan of this chunk's bucket histogram + global bases
    int carry = 0;
    for (int b0 = 0; b0 < nbkt; b0 += 256) {
        int b = b0 + t;
        int v = (b < nbkt) ? hist2d[(size_t)blockIdx.x * nbkt + b] : 0;
        int inc = v;
        for (int o = 1; o < 64; o <<= 1) { int u = __shfl_up(inc, o); if (lane >= o) inc += u; }
        if (lane == 63) wtot[wv] = inc;
        __syncthreads();
        int add = carry;
        for (int k = 0; k < wv; ++k) add += wtot[k];
        if (b < nbkt) {
            excl[b]  = add + inc - v;
            hist[b]  = 0;
            gbase[b] = bstart[b] + base2d[(size_t)blockIdx.x * nbkt + b];
        }
        carry += wtot[0] + wtot[1] + wtot[2] + wtot[3];
        __syncthreads();
    }

    // LDS scatter into bucket-sorted order
#pragma unroll
    for (int j = 0; j < EPT; ++j) {
        int i = base + j * 256 + t;
        if (i < e) {
            int d = dst[i];
            unsigned int pk = (unsigned int)src[i] | ((unsigned int)d << 16);   // N < 65536
            int bk = d >> BKT_SH;
            int p  = excl[bk] + atomicAdd(&hist[bk], 1);
            stage[p] = pk;
        }
    }
    __syncthreads();

    // coalesced flush
    int nchunk = min(CHUNK, e - base);
    for (int i = t; i < nchunk; i += 256) {
        unsigned int u = stage[i];
        int b = (int)(u >> 16) >> BKT_SH;
        bpack[gbase[b] + (i - excl[b])] = u;
    }
}

// ---------------- pass B: per-bucket counting sort -> dinv/row_start/csr_src ----------------
__global__ void k_binB(const int* __restrict__ bstart, const unsigned int* __restrict__ bpack,
                       int* __restrict__ row_start, float* __restrict__ dinv,
                       int* __restrict__ csr_src, int n, int e, int nbkt) {
    __shared__ int hist[BKT_N];
    __shared__ int excl[BKT_N];
    __shared__ int wtot[4];
    const int t = threadIdx.x;
    const int b = blockIdx.x;
    const int beg = bstart[b], end = bstart[b + 1];
    const int nodebase = b << BKT_SH;
    const int nloc = min(BKT_N, n - nodebase);

    for (int i = t; i < nloc; i += 256) hist[i] = 0;
    __syncthreads();
    for (int i = beg + t; i < end; i += 256)
        atomicAdd(&hist[(int)(bpack[i] >> 16) - nodebase], 1);
    __syncthreads();

    // exclusive scan of hist[0..nloc) (nloc <= 128 < 256: single pass)
    {
        int idx = t;
        int v = (idx < nloc) ? hist[idx] : 0;
        int inc = v; int lane = t & 63; int wv = t >> 6;
        for (int o = 1; o < 64; o <<= 1) { int u = __shfl_up(inc, o); if (lane >= o) inc += u; }
        if (lane == 63) wtot[wv] = inc;
        __syncthreads();
        int add = 0;
        for (int k = 0; k < wv; ++k) add += wtot[k];
        if (idx < nloc) excl[idx] = add + inc - v;
    }
    __syncthreads();

    for (int i = t; i < nloc; i += 256) {
        row_start[nodebase + i] = beg + excl[i];
        dinv[nodebase + i] = rsqrtf((float)hist[i] + 1.0f);   // +1 self loop
    }
    if (b == nbkt - 1 && t == 0) row_start[n] = e;
    __syncthreads();
    for (int i = t; i < nloc; i += 256) hist[i] = 0;   // reuse as cursors
    __syncthreads();

    for (int i = beg + t; i < end; i += 256) {
        unsigned int u = bpack[i];
        int dl = (int)(u >> 16) - nodebase;
        int p = beg + excl[dl] + atomicAdd(&hist[dl], 1);
        csr_src[p] = (int)(u & 0xFFFFu);
    }
}

// ---------------- GEMM1: h1b = bf16(dinv[row] * (X @ W1))  (N x 64) ----------------
__global__ void k_gemm1(const float* __restrict__ X, const float* __restrict__ W1,
                        const float* __restrict__ dinv, unsigned short* __restrict__ h1b, int n) {
    __shared__ float xt[C_IN][64];
    __shared__ float wl[C_IN * C_HID];
    const int t = threadIdx.x;
    const int row0 = blockIdx.x * 64;

    for (int i = t; i < C_IN * C_HID; i += 256) wl[i] = W1[i];
    {
        int r = t >> 2, q = t & 3;
        int grow = row0 + r;
        for (int j = 0; j < 8; ++j) {
            int k = q * 32 + j * 4;
            float4 v = make_float4(0.f, 0.f, 0.f, 0.f);
            if (grow < n) v = *(const float4*)(X + (size_t)grow * C_IN + k);
            xt[k + 0][r] = v.x; xt[k + 1][r] = v.y; xt[k + 2][r] = v.z; xt[k + 3][r] = v.w;
        }
    }
    __syncthreads();

    const int rg = t >> 4, cg = t & 15;
    const int r0 = rg * 4, c0 = cg * 4;
    float acc[4][4] = {};
#pragma unroll 4
    for (int k = 0; k < C_IN; ++k) {
        float4 a = *(const float4*)&xt[k][r0];
        float4 b = *(const float4*)&wl[k * C_HID + c0];
        acc[0][0] = fmaf(a.x, b.x, acc[0][0]); acc[0][1] = fmaf(a.x, b.y, acc[0][1]);
        acc[0][2] = fmaf(a.x, b.z, acc[0][2]); acc[0][3] = fmaf(a.x, b.w, acc[0][3]);
        acc[1][0] = fmaf(a.y, b.x, acc[1][0]); acc[1][1] = fmaf(a.y, b.y, acc[1][1]);
        acc[1][2] = fmaf(a.y, b.z, acc[1][2]); acc[1][3] = fmaf(a.y, b.w, acc[1][3]);
        acc[2][0] = fmaf(a.z, b.x, acc[2][0]); acc[2][1] = fmaf(a.z, b.y, acc[2][1]);
        acc[2][2] = fmaf(a.z, b.z, acc[2][2]); acc[2][3] = fmaf(a.z, b.w, acc[2][3]);
        acc[3][0] = fmaf(a.w, b.x, acc[3][0]); acc[3][1] = fmaf(a.w, b.y, acc[3][1]);
        acc[3][2] = fmaf(a.w, b.z, acc[3][2]); acc[3][3] = fmaf(a.w, b.w, acc[3][3]);
    }
#pragma unroll
    for (int i = 0; i < 4; ++i) {
        int row = row0 + r0 + i;
        if (row < n) {
            float di = dinv[row];
            ushort4 o;
            o.x = f2bf(di * acc[i][0]); o.y = f2bf(di * acc[i][1]);
            o.z = f2bf(di * acc[i][2]); o.w = f2bf(di * acc[i][3]);
            *(ushort4*)(h1b + (size_t)row * C_HID + c0) = o;
        }
    }
}

// ------- fused layer-1 aggregate + bias + relu + GEMM2 (packed-dword gather) -------
// 512 threads = 8 waves = 8 nodes per block. Gather: lane = (h, c2); half h handles
// edge k+2i+h, dword c2 = channels (2c2, 2c2+1). 2 edges per wave load round.
__global__ void k_agg1g2(const int* __restrict__ row_start, const int* __restrict__ csr_src,
                         const unsigned short* __restrict__ h1b, const float* __restrict__ dinv,
                         const float* __restrict__ b1, const float* __restrict__ W2,
                         unsigned short* __restrict__ h2b, int n) {
    __shared__ float wl[C_HID * C_OUT];       // 10 KB
    __shared__ float rowbuf[8][C_HID];        // 2 KB
    const int t = threadIdx.x;
    for (int i = t; i < C_HID * C_OUT; i += 512) wl[i] = W2[i];
    __syncthreads();

    const int wid  = t >> 6;
    const int lane = t & 63;
    const int node = blockIdx.x * 8 + wid;
    if (node >= n) return;

    const int h  = lane >> 5;       // which edge of the pair
    const int c2 = lane & 31;       // dword index within row
    const unsigned int* h1d = (const unsigned int*)h1b;

    int beg = row_start[node], end = row_start[node + 1];
    float alo[4] = {0.f, 0.f, 0.f, 0.f}, ahi[4] = {0.f, 0.f, 0.f, 0.f};
    {   // self term (prescaled by dinv[node]); only half h==0 contributes
        unsigned int u = h1d[(size_t)node * H1DW + c2];
        if (h == 0) {
            alo[0] = __uint_as_float(u << 16);
            ahi[0] = __uint_as_float(u & 0xFFFF0000u);
        }
    }
    for (int j = beg; j < end; j += 64) {
        int sv = (j + lane < end) ? csr_src[j + lane] : 0;
        int m  = min(64, end - j);
        for (int k = 0; k < m; k += 8) {
#pragma unroll
            for (int i = 0; i < 4; ++i) {
                int idx = k + 2 * i + h;                 // <= 63 always
                int s   = __shfl(sv, idx);
                float f = (idx < m) ? 1.f : 0.f;
                unsigned int u = h1d[(size_t)s * H1DW + c2];
                alo[i] = fmaf(f, __uint_as_float(u << 16), alo[i]);
                ahi[i] = fmaf(f, __uint_as_float(u & 0xFFFF0000u), ahi[i]);
            }
        }
    }
    float lo = (alo[0] + alo[1]) + (alo[2] + alo[3]);
    float hi = (ahi[0] + ahi[1]) + (ahi[2] + ahi[3]);
    lo += __shfl_xor(lo, 32);                            // combine halves
    hi += __shfl_xor(hi, 32);

    float di = dinv[node];
    if (h == 0) {                                        // lanes 0-31: bias + relu -> rowbuf
        float2 bb = *(const float2*)(b1 + 2 * c2);
        float vlo = di * lo + bb.x;
        float vhi = di * hi + bb.y;
        rowbuf[wid][2 * c2]     = vlo > 0.f ? vlo : 0.f;
        rowbuf[wid][2 * c2 + 1] = vhi > 0.f ? vhi : 0.f;
    }
    // matvec (same-wave RAW on rowbuf): h2[c] = sum_k row[k]*W2[k][c]
    if (lane < C_OUT) {
        float acc2 = 0.f;
#pragma unroll 8
        for (int k = 0; k < C_HID; ++k)
            acc2 = fmaf(rowbuf[wid][k], wl[k * C_OUT + lane], acc2);
        h2b[(size_t)node * C_OUT + lane] = f2bf(di * acc2);
    }
}

// ------- layer-2 aggregate + bias + log_softmax (packed-dword gather, 3 edges/round) -------
// lane = (h3, c2): h3 = lane/20 in {0,1,2} (lanes 60-63 discarded), c2 = dword 0..19.
__global__ void k_agg2(const int* __restrict__ row_start, const int* __restrict__ csr_src,
                       const unsigned short* __restrict__ h2b, const float* __restrict__ dinv,
                       const float* __restrict__ b2, float* __restrict__ out, int n) {
    int node = (blockIdx.x * 256 + threadIdx.x) >> 6;
    int lane = threadIdx.x & 63;
    if (node >= n) return;
    const int h3 = lane / 20;
    const int c2 = lane - h3 * 20;
    const unsigned int* h2d = (const unsigned int*)h2b;

    int beg = row_start[node], end = row_start[node + 1];
    float alo[4] = {0.f, 0.f, 0.f, 0.f}, ahi[4] = {0.f, 0.f, 0.f, 0.f};
    if (h3 == 0) {   // self term
        unsigned int u = h2d[(size_t)node * H2DW + c2];
        alo[0] = __uint_as_float(u << 16);
        ahi[0] = __uint_as_float(u & 0xFFFF0000u);
    }
    for (int j = beg; j < end; j += 64) {
        int sv = (j + lane < end) ? csr_src[j + lane] : 0;
        int m = min(64, end - j);
        for (int k = 0; k < m; k += 12) {
#pragma unroll
            for (int i = 0; i < 4; ++i) {
                int idx = k + 3 * i + h3;
                int s = __shfl(sv, idx & 63);
                float f = (idx < m) ? 1.f : 0.f;        // h3==3 lanes' results are discarded
                unsigned int u = h2d[(size_t)s * H2DW + c2];
                alo[i] = fmaf(f, __uint_as_float(u << 16), alo[i]);
                ahi[i] = fmaf(f, __uint_as_float(u & 0xFFFF0000u), ahi[i]);
            }
        }
    }
    float lo = (alo[0] + alo[1]) + (alo[2] + alo[3]);
    float hi = (ahi[0] + ahi[1]) + (ahi[2] + ahi[3]);
    // combine thirds: lanes 0-19 pick up partials from lanes c2+20 (h3=1), c2+40 (h3=2)
    float lA = __shfl(lo, c2 + 20), lB = __shfl(lo, c2 + 40);
    float hA = __shfl(hi, c2 + 20), hB = __shfl(hi, c2 + 40);
    lo += lA + lB;
    hi += hA + hB;

    float di = dinv[node];
    float vlo = -INFINITY, vhi = -INFINITY, ex = 0.f;
    if (h3 == 0) {
        float2 bb = *(const float2*)(b2 + 2 * c2);
        vlo = di * lo + bb.x;
        vhi = di * hi + bb.y;
    }
    float mx = fmaxf(vlo, vhi);
    for (int off = 16; off; off >>= 1) mx = fmaxf(mx, __shfl_xor(mx, off));   // reduce lanes 0-31
    if (h3 == 0) ex = expf(vlo - mx) + expf(vhi - mx);
    float ss = ex;
    for (int off = 16; off; off >>= 1) ss += __shfl_xor(ss, off);
    float lse = mx + logf(ss);
    if (h3 == 0)
        *(float2*)(out + (size_t)node * C_OUT + 2 * c2) = make_float2(vlo - lse, vhi - lse);
}

extern "C" void kernel_launch(void* const* d_in, const int* in_sizes, int n_in,
                              void* d_out, int out_size, void* d_ws, size_t ws_size,
                              hipStream_t stream) {
    const float* X   = (const float*)d_in[0];
    const int*   src = (const int*)d_in[1];
    const int*   dst = (const int*)d_in[2];
    const float* W1  = (const float*)d_in[3];
    const float* b1  = (const float*)d_in[4];
    const float* W2  = (const float*)d_in[5];
    const float* b2  = (const float*)d_in[6];
    float* out = (float*)d_out;

    const int N = in_sizes[0] / C_IN;
    const int E = in_sizes[1];
    const int NBKT = (N + BKT_N - 1) >> BKT_SH;          // 391
    const int nchunks = (E + CHUNK - 1) / CHUNK;         // 782

    // workspace layout
    char* ws = (char*)d_ws;
    size_t off = 0;
    auto take = [&](size_t bytes) { char* p = ws + off; off = (off + bytes + 255) & ~(size_t)255; return p; };
    int*   hist2d    = (int*)  take((size_t)nchunks * NBKT * 4);
    int*   base2d    = (int*)  take((size_t)nchunks * NBKT * 4);
    int*   tot       = (int*)  take(512 * 4);
    int*   bstart    = (int*)  take(512 * 4);
    unsigned int* bpack = (unsigned int*)take((size_t)E * 4);
    int*   csr_src   = (int*)  take((size_t)E * 4);
    int*   row_start = (int*)  take((size_t)(N + 1) * 4);
    float* dinv      = (float*)take((size_t)N * 4);
    unsigned short* h1b = (unsigned short*)take((size_t)N * C_HID * 2);
    unsigned short* h2b = (unsigned short*)take((size_t)N * C_OUT * 2);

    k_hist    <<<nchunks, 256, 0, stream>>>(dst, hist2d, E, NBKT);
    k_bktscan <<<NBKT, 256, 0, stream>>>(hist2d, base2d, tot, nchunks, NBKT);
    k_scan_bkt<<<1, 256, 0, stream>>>(tot, bstart, NBKT, E);
    k_binA    <<<nchunks, 256, 0, stream>>>(src, dst, bstart, hist2d, base2d, bpack, E, NBKT);
    k_binB    <<<NBKT, 256, 0, stream>>>(bstart, bpack, row_start, dinv, csr_src, N, E, NBKT);

    k_gemm1   <<<(N + 63) / 64, 256, 0, stream>>>(X, W1, dinv, h1b, N);
    k_agg1g2  <<<(N + 7) / 8, 512, 0, stream>>>(row_start, csr_src, h1b, dinv, b1, W2, h2b, N);
    k_agg2    <<<((size_t)N * 64 + 255) / 256, 256, 0, stream>>>(row_start, csr_src, h2b, dinv, b2, out, N);
}